// Round 3
// baseline (4991.614 us; speedup 1.0000x reference)
//
#include <hip/hip_runtime.h>
#include <math.h>

typedef unsigned short u16;
typedef u16 u16x8 __attribute__((ext_vector_type(8)));
typedef u16 u16x4 __attribute__((ext_vector_type(4)));
typedef short short8 __attribute__((ext_vector_type(8)));
typedef float f32x4 __attribute__((ext_vector_type(4)));

#define NE 768
#define NH 12
#define NL 12
#define NV 50257
#define NVP 50304   // NV padded to 128 multiple for unguarded B staging
#define HD 64
#define DFF 3072
#define NB 2
#define SL 1024
#define TT 2048     // NB*SL tokens
#define QKVD 2304   // 3*NE

static __device__ __forceinline__ u16 f2bf(float f){
  unsigned int x; __builtin_memcpy(&x, &f, 4);
  x = (x + 0x7FFFu + ((x >> 16) & 1u)) >> 16;
  return (u16)x;
}

typedef const __attribute__((address_space(1))) unsigned int* gas1_t;
typedef __attribute__((address_space(3))) unsigned int* las3_t;
static __device__ __forceinline__ void gload16(const u16* g, u16* l){
  __builtin_amdgcn_global_load_lds((gas1_t)(const void*)g, (las3_t)(void*)l, 16, 0, 0);
}

// ---------------- fp32 -> bf16 convert (vectorized) ----------------
__global__ void k_cvt4(const float4* __restrict__ in, u16x4* __restrict__ out, long n4){
  long i = (long)blockIdx.x * blockDim.x + threadIdx.x;
  long st = (long)gridDim.x * blockDim.x;
  for (; i < n4; i += st){
    float4 v = in[i];
    u16x4 o = { f2bf(v.x), f2bf(v.y), f2bf(v.z), f2bf(v.w) };
    out[i] = o;
  }
}

// ------ fp32 [L][K][N] -> bf16 [L][N][K] transpose-convert, all layers ------
__global__ __launch_bounds__(256) void k_transpose_cvt_all(const float* __restrict__ in0,
    u16* __restrict__ out0, int K, int N){
  __shared__ u16 tile[32][33];
  const float* in = in0 + (long)blockIdx.z * K * N;
  u16* out = out0 + (long)blockIdx.z * N * K;
  int n0 = blockIdx.x * 32, k0 = blockIdx.y * 32;
#pragma unroll
  for (int i = 0; i < 4; ++i){
    int e = threadIdx.x + i * 256;
    int r = e >> 5, c = e & 31;          // r: k, c: n
    tile[r][c] = f2bf(in[(long)(k0 + r) * N + (n0 + c)]);
  }
  __syncthreads();
#pragma unroll
  for (int i = 0; i < 4; ++i){
    int e = threadIdx.x + i * 256;
    int r = e >> 5, c = e & 31;          // r: n, c: k
    out[(long)(n0 + r) * K + (k0 + c)] = tile[c][r];
  }
}

// ---------------- LayerNorm: f32 [TT][768] -> bf16 ----------------
__global__ __launch_bounds__(256) void k_layernorm(const float* __restrict__ x,
    const float* __restrict__ g, const float* __restrict__ b, u16* __restrict__ out){
  int row = blockIdx.x;
  const float* xr = x + (long)row * NE;
  int t = threadIdx.x;
  float v[3];
  v[0] = xr[t]; v[1] = xr[t + 256]; v[2] = xr[t + 512];
  float s = v[0] + v[1] + v[2];
  float sq = v[0]*v[0] + v[1]*v[1] + v[2]*v[2];
  __shared__ float red[8];
#pragma unroll
  for (int o = 32; o; o >>= 1){ s += __shfl_xor(s, o); sq += __shfl_xor(sq, o); }
  int wid = t >> 6, lane = t & 63;
  if (!lane){ red[wid] = s; red[4 + wid] = sq; }
  __syncthreads();
  s  = red[0] + red[1] + red[2] + red[3];
  sq = red[4] + red[5] + red[6] + red[7];
  float mean = s * (1.f / NE);
  float var  = sq * (1.f / NE) - mean * mean;
  float rs = rsqrtf(var + 1e-5f);
  u16* orow = out + (long)row * NE;
#pragma unroll
  for (int i = 0; i < 3; ++i){
    int c = t + i * 256;
    orow[c] = f2bf((v[i] - mean) * rs * g[c] + b[c]);
  }
}

// ---------------- fused causal flash attention ----------------
// qkv: [TT][2304] bf16 (Q|K|V each 768, head h at cols h*64..+63)
// out: [TT][768] bf16
// grid: (8 q-blocks of 128, 24 bh). 256 threads / 4 waves; wave owns 32 q rows.
__global__ __launch_bounds__(256) void k_flash(const u16* __restrict__ qkv,
    u16* __restrict__ out){
  __shared__ u16 Ps[128 * 72];   // Q staging, then P tile (q x kv, 64 cols used)
  __shared__ u16 Ks[64 * 72];    // K tile (kv x d)
  __shared__ u16 Vt[64 * 72];    // V^T tile (d x kv)
  const int qb = blockIdx.x, z = blockIdx.y;
  const int b = z / NH, h = z % NH;
  const int q0 = qb * 128;
  const u16* Qb = qkv + (long)(b * SL) * QKVD + h * HD;
  const u16* Kb = Qb + NE;
  const u16* Vb = Qb + 2 * NE;
  const int t = threadIdx.x, lane = t & 63, wid = t >> 6;
  const int lr = lane & 15, lk = lane >> 4;
  const int wm = wid * 32;
  // stage Q [128][64] into Ps
  {
    int r = t >> 3, c = (t & 7) * 8;
#pragma unroll
    for (int i = 0; i < 4; ++i){
      u16x8 v = *(const u16x8*)(Qb + (long)(q0 + r + i * 32) * QKVD + c);
      *(u16x8*)&Ps[(r + i * 32) * 72 + c] = v;
    }
  }
  __syncthreads();
  short8 aq[2][2];
#pragma unroll
  for (int i = 0; i < 2; ++i)
#pragma unroll
    for (int c = 0; c < 2; ++c)
      aq[i][c] = *(const short8*)&Ps[(wm + i * 16 + lr) * 72 + c * 32 + lk * 8];
  f32x4 o[2][4] = {};
  float m[2][4], l[2][4];
#pragma unroll
  for (int i = 0; i < 2; ++i)
#pragma unroll
    for (int r = 0; r < 4; ++r){ m[i][r] = -3e38f; l[i][r] = 0.f; }
  const int nt = qb * 2 + 2;
  for (int kt = 0; kt < nt; ++kt){
    const int kv0 = kt * 64;
    __syncthreads();
    // stage K [64][72]
    {
      int r = t >> 3, c = (t & 7) * 8;
#pragma unroll
      for (int i = 0; i < 2; ++i){
        u16x8 v = *(const u16x8*)(Kb + (long)(kv0 + r + i * 32) * QKVD + c);
        *(u16x8*)&Ks[(r + i * 32) * 72 + c] = v;
      }
    }
    // stage V^T [64 d][72]: coalesced row loads, scalar transposed writes
    {
      int d = t & 63, r0 = t >> 6;
#pragma unroll
      for (int i = 0; i < 16; ++i){
        int r = r0 + i * 4;
        Vt[d * 72 + r] = Vb[(long)(kv0 + r) * QKVD + d];
      }
    }
    __syncthreads();
    // S = Q K^T  (rows: wave's 32, cols: all 64)
    f32x4 s[2][4] = {};
#pragma unroll
    for (int c = 0; c < 2; ++c){
      short8 bf[4];
#pragma unroll
      for (int j = 0; j < 4; ++j)
        bf[j] = *(const short8*)&Ks[(j * 16 + lr) * 72 + c * 32 + lk * 8];
#pragma unroll
      for (int i = 0; i < 2; ++i)
#pragma unroll
        for (int j = 0; j < 4; ++j)
          s[i][j] = __builtin_amdgcn_mfma_f32_16x16x32_bf16(aq[i][c], bf[j], s[i][j], 0, 0, 0);
    }
    const bool dm = (kv0 + 63 > q0);
    // online softmax; write P (bf16) into wave's rows of Ps
#pragma unroll
    for (int i = 0; i < 2; ++i){
#pragma unroll
      for (int r = 0; r < 4; ++r){
        const int rowl = wm + i * 16 + lk * 4 + r;
        const int row = q0 + rowl;
        float pm = -3e38f;
#pragma unroll
        for (int j = 0; j < 4; ++j){
          float v = s[i][j][r] * 0.125f;
          if (dm && (kv0 + j * 16 + lr > row)) v = -3e38f;
          s[i][j][r] = v;
          pm = fmaxf(pm, v);
        }
#pragma unroll
        for (int off = 1; off < 16; off <<= 1) pm = fmaxf(pm, __shfl_xor(pm, off));
        float mn = fmaxf(m[i][r], pm);
        float f = __expf(m[i][r] - mn);
        m[i][r] = mn;
        float ps = 0.f;
#pragma unroll
        for (int j = 0; j < 4; ++j){
          float p = __expf(s[i][j][r] - mn);
          ps += p;
          Ps[rowl * 72 + j * 16 + lr] = f2bf(p);
        }
#pragma unroll
        for (int off = 1; off < 16; off <<= 1) ps += __shfl_xor(ps, off);
        l[i][r] = l[i][r] * f + ps;
#pragma unroll
        for (int j = 0; j < 4; ++j) o[i][j][r] *= f;
      }
    }
    // O += P V  (A from Ps own rows, B from Vt)
#pragma unroll
    for (int c = 0; c < 2; ++c){
      short8 pa[2], vb[4];
#pragma unroll
      for (int i = 0; i < 2; ++i)
        pa[i] = *(const short8*)&Ps[(wm + i * 16 + lr) * 72 + c * 32 + lk * 8];
#pragma unroll
      for (int j = 0; j < 4; ++j)
        vb[j] = *(const short8*)&Vt[(j * 16 + lr) * 72 + c * 32 + lk * 8];
#pragma unroll
      for (int i = 0; i < 2; ++i)
#pragma unroll
        for (int j = 0; j < 4; ++j)
          o[i][j] = __builtin_amdgcn_mfma_f32_16x16x32_bf16(pa[i], vb[j], o[i][j], 0, 0, 0);
    }
  }
  // epilogue: normalize and store
  u16* O = out + (long)(b * SL + q0) * NE + h * HD;
#pragma unroll
  for (int i = 0; i < 2; ++i){
#pragma unroll
    for (int r = 0; r < 4; ++r){
      float inv = 1.f / l[i][r];
#pragma unroll
      for (int j = 0; j < 4; ++j)
        O[(long)(wm + i * 16 + lk * 4 + r) * NE + j * 16 + lr] = f2bf(o[i][j][r] * inv);
    }
  }
}

// ---------------- generic bf16 MFMA GEMM, B^T layout (m97 structure) ----------------
// modes: 0 bf16 raw, 1 bf16 +bias, 2 bf16 +bias +gelu(erf), 3 f32 raw, 4 f32 +bias +res
struct GemmP {
  const u16* A; const u16* B; void* C;
  const float* bias; const float* res;
  int M, N, K, lda, ldb, ldc, mode;
};

__global__ __launch_bounds__(256) void k_gemm_bt(GemmP p){
  __shared__ u16 As[128 * 32];
  __shared__ u16 Bs[128 * 32];
  const int m0 = blockIdx.x * 128, n0 = blockIdx.y * 128;
  const u16* A = p.A;
  const u16* B = p.B;
  const int t = threadIdx.x, lane = t & 63, wid = t >> 6;
  const int wm = (wid >> 1) * 64, wn = (wid & 1) * 64;
  const int lr = lane & 15, lk = lane >> 4;
  const int srow0 = wid * 32 + (lane >> 2);
  const int sseg  = (lane & 3) * 8;
  f32x4 acc[4][4] = {};
  for (int k0 = 0; k0 < p.K; k0 += 32){
    const u16* Ab = A + (long)(m0 + srow0) * p.lda + k0 + sseg;
    const u16* Bb = B + (long)(n0 + srow0) * p.ldb + k0 + sseg;
    gload16(Ab, As + (wid * 2 + 0) * 512);
    gload16(Ab + 16 * p.lda, As + (wid * 2 + 1) * 512);
    gload16(Bb, Bs + (wid * 2 + 0) * 512);
    gload16(Bb + 16 * p.ldb, Bs + (wid * 2 + 1) * 512);
    __syncthreads();
    short8 af[4], bfr[4];
#pragma unroll
    for (int i = 0; i < 4; ++i) af[i]  = *(const short8*)&As[(wm + i * 16 + lr) * 32 + lk * 8];
#pragma unroll
    for (int j = 0; j < 4; ++j) bfr[j] = *(const short8*)&Bs[(wn + j * 16 + lr) * 32 + lk * 8];
#pragma unroll
    for (int i = 0; i < 4; ++i)
#pragma unroll
      for (int j = 0; j < 4; ++j)
        acc[i][j] = __builtin_amdgcn_mfma_f32_16x16x32_bf16(af[i], bfr[j], acc[i][j], 0, 0, 0);
    __syncthreads();
  }
#pragma unroll
  for (int i = 0; i < 4; ++i){
#pragma unroll
    for (int r = 0; r < 4; ++r){
      int row = m0 + wm + i * 16 + lk * 4 + r;
      if (row >= p.M) continue;
#pragma unroll
      for (int j = 0; j < 4; ++j){
        int col = n0 + wn + j * 16 + lr;
        if (col >= p.N) continue;
        float v = acc[i][j][r];
        if (p.mode == 1 || p.mode == 2 || p.mode == 4) v += p.bias[col];
        if (p.mode == 2) v = 0.5f * v * (1.f + erff(v * 0.70710678118f));
        long idx = (long)row * p.ldc + col;
        if (p.mode == 4) v += p.res[idx];
        if (p.mode >= 3) ((float*)p.C)[idx] = v;
        else             ((u16*)p.C)[idx] = f2bf(v);
      }
    }
  }
}

static inline void gemm(hipStream_t s, const u16* A, int lda, const u16* B, int ldb,
    void* C, int ldc, int M, int N, int K, const float* bias, const float* res, int mode){
  GemmP p{ A, B, C, bias, res, M, N, K, lda, ldb, ldc, mode };
  dim3 g(M / 128, (N + 127) / 128, 1);
  k_gemm_bt<<<g, 256, 0, s>>>(p);
}

extern "C" void kernel_launch(void* const* d_in, const int* in_sizes, int n_in,
                              void* d_out, int out_size, void* d_ws, size_t ws_size,
                              hipStream_t stream){
  (void)in_sizes; (void)n_in; (void)out_size; (void)ws_size;
  const float* x    = (const float*)d_in[0];
  const float* Wqkv = (const float*)d_in[1];
  const float* bqkv = (const float*)d_in[2];
  const float* Wo   = (const float*)d_in[3];
  const float* bo   = (const float*)d_in[4];
  const float* W1   = (const float*)d_in[5];
  const float* b1   = (const float*)d_in[6];
  const float* W2   = (const float*)d_in[7];
  const float* b2   = (const float*)d_in[8];
  const float* ln1g = (const float*)d_in[9];
  const float* ln1b = (const float*)d_in[10];
  const float* ln2g = (const float*)d_in[11];
  const float* ln2b = (const float*)d_in[12];
  const float* lnfg = (const float*)d_in[13];
  const float* lnfb = (const float*)d_in[14];
  const float* Wlm  = (const float*)d_in[15];

  char* ws = (char*)d_ws;
  size_t off = 0;
  auto alloc = [&](size_t bytes){ void* p = ws + off; off += (bytes + 255) & ~255UL; return p; };
  float* h      = (float*)alloc((size_t)TT * NE * 4);
  u16*   a      = (u16*)  alloc((size_t)TT * NE * 2);
  u16*   qkv    = (u16*)  alloc((size_t)TT * QKVD * 2);
  u16*   attno  = (u16*)  alloc((size_t)TT * NE * 2);
  u16*   ffm    = (u16*)  alloc((size_t)TT * DFF * 2);
  u16*   wqkvT  = (u16*)  alloc((size_t)NL * QKVD * NE * 2);
  u16*   woT    = (u16*)  alloc((size_t)NL * NE * NE * 2);
  u16*   w1T    = (u16*)  alloc((size_t)NL * DFF * NE * 2);
  u16*   w2T    = (u16*)  alloc((size_t)NL * NE * DFF * 2);
  u16*   wlmB   = (u16*)  alloc((size_t)NVP * NE * 2);

  // h = x
  hipMemcpyAsync(h, x, (size_t)TT * NE * 4, hipMemcpyDeviceToDevice, stream);
  // weight conversions: all layers in 4 launches + LM head
  k_transpose_cvt_all<<<dim3(QKVD / 32, NE / 32, NL), 256, 0, stream>>>(Wqkv, wqkvT, NE, QKVD);
  k_transpose_cvt_all<<<dim3(NE / 32, NE / 32, NL),   256, 0, stream>>>(Wo,   woT,   NE, NE);
  k_transpose_cvt_all<<<dim3(DFF / 32, NE / 32, NL),  256, 0, stream>>>(W1,   w1T,   NE, DFF);
  k_transpose_cvt_all<<<dim3(NE / 32, DFF / 32, NL),  256, 0, stream>>>(W2,   w2T,   DFF, NE);
  k_cvt4<<<2048, 256, 0, stream>>>((const float4*)Wlm, (u16x4*)wlmB, (long)NV * NE / 4);
  hipMemsetAsync(wlmB + (size_t)NV * NE, 0, (size_t)(NVP - NV) * NE * 2, stream);

  for (int L = 0; L < NL; ++L){
    // ln1 -> a
    k_layernorm<<<TT, 256, 0, stream>>>(h, ln1g + L * NE, ln1b + L * NE, a);
    // qkv = a @ Wqkv + bqkv  (bf16)
    gemm(stream, a, NE, wqkvT + (size_t)L * QKVD * NE, NE, qkv, QKVD, TT, QKVD, NE,
         bqkv + (size_t)L * QKVD, nullptr, 1);
    // fused causal attention -> attno
    k_flash<<<dim3(SL / 128, NB * NH), 256, 0, stream>>>(qkv, attno);
    // h += attno @ Wo + bo
    gemm(stream, attno, NE, woT + (size_t)L * NE * NE, NE, h, NE, TT, NE, NE,
         bo + (size_t)L * NE, h, 4);
    // ln2 -> a
    k_layernorm<<<TT, 256, 0, stream>>>(h, ln2g + L * NE, ln2b + L * NE, a);
    // ffm = gelu(a @ W1 + b1)
    gemm(stream, a, NE, w1T + (size_t)L * DFF * NE, NE, ffm, DFF, TT, DFF, NE,
         b1 + (size_t)L * DFF, nullptr, 2);
    // h += ffm @ W2 + b2
    gemm(stream, ffm, DFF, w2T + (size_t)L * NE * DFF, DFF, h, NE, TT, NE, DFF,
         b2 + (size_t)L * NE, h, 4);
  }
  // final LN -> a
  k_layernorm<<<TT, 256, 0, stream>>>(h, lnfg, lnfb, a);
  // logits = a @ Wlm^T  (f32 out)
  gemm(stream, a, NE, wlmB, NE, d_out, NV, TT, NV, NE,
       nullptr, nullptr, 3);
}

// Round 4
// 2948.483 us; speedup vs baseline: 1.6929x; 1.6929x over previous
//
#include <hip/hip_runtime.h>
#include <math.h>

typedef unsigned short u16;
typedef u16 u16x8 __attribute__((ext_vector_type(8)));
typedef u16 u16x4 __attribute__((ext_vector_type(4)));
typedef short short8 __attribute__((ext_vector_type(8)));
typedef float f32x4 __attribute__((ext_vector_type(4)));

#define NE 768
#define NH 12
#define NL 12
#define NV 50257
#define NVP 50304   // NV padded to 128 multiple for unguarded B staging
#define HD 64
#define DFF 3072
#define NB 2
#define SL 1024
#define TT 2048     // NB*SL tokens
#define QKVD 2304   // 3*NE

static __device__ __forceinline__ u16 f2bf(float f){
  unsigned int x; __builtin_memcpy(&x, &f, 4);
  x = (x + 0x7FFFu + ((x >> 16) & 1u)) >> 16;
  return (u16)x;
}

typedef const __attribute__((address_space(1))) unsigned int* gas1_t;
typedef __attribute__((address_space(3))) unsigned int* las3_t;
static __device__ __forceinline__ void gload16(const u16* g, u16* l){
  __builtin_amdgcn_global_load_lds((gas1_t)(const void*)g, (las3_t)(void*)l, 16, 0, 0);
}

// ---------------- fp32 -> bf16 convert (vectorized) ----------------
__global__ void k_cvt4(const float4* __restrict__ in, u16x4* __restrict__ out, long n4){
  long i = (long)blockIdx.x * blockDim.x + threadIdx.x;
  long st = (long)gridDim.x * blockDim.x;
  for (; i < n4; i += st){
    float4 v = in[i];
    u16x4 o = { f2bf(v.x), f2bf(v.y), f2bf(v.z), f2bf(v.w) };
    out[i] = o;
  }
}

// ------ fp32 [L][K][N] -> bf16 [L][N][K] transpose-convert, all layers ------
__global__ __launch_bounds__(256) void k_transpose_cvt_all(const float* __restrict__ in0,
    u16* __restrict__ out0, int K, int N){
  __shared__ u16 tile[32][33];
  const float* in = in0 + (long)blockIdx.z * K * N;
  u16* out = out0 + (long)blockIdx.z * N * K;
  int n0 = blockIdx.x * 32, k0 = blockIdx.y * 32;
#pragma unroll
  for (int i = 0; i < 4; ++i){
    int e = threadIdx.x + i * 256;
    int r = e >> 5, c = e & 31;          // r: k, c: n
    tile[r][c] = f2bf(in[(long)(k0 + r) * N + (n0 + c)]);
  }
  __syncthreads();
#pragma unroll
  for (int i = 0; i < 4; ++i){
    int e = threadIdx.x + i * 256;
    int r = e >> 5, c = e & 31;          // r: n, c: k
    out[(long)(n0 + r) * K + (k0 + c)] = tile[c][r];
  }
}

// ---------------- LayerNorm: f32 [TT][768] -> bf16 ----------------
__global__ __launch_bounds__(256) void k_layernorm(const float* __restrict__ x,
    const float* __restrict__ g, const float* __restrict__ b, u16* __restrict__ out){
  int row = blockIdx.x;
  const float* xr = x + (long)row * NE;
  int t = threadIdx.x;
  float v[3];
  v[0] = xr[t]; v[1] = xr[t + 256]; v[2] = xr[t + 512];
  float s = v[0] + v[1] + v[2];
  float sq = v[0]*v[0] + v[1]*v[1] + v[2]*v[2];
  __shared__ float red[8];
#pragma unroll
  for (int o = 32; o; o >>= 1){ s += __shfl_xor(s, o); sq += __shfl_xor(sq, o); }
  int wid = t >> 6, lane = t & 63;
  if (!lane){ red[wid] = s; red[4 + wid] = sq; }
  __syncthreads();
  s  = red[0] + red[1] + red[2] + red[3];
  sq = red[4] + red[5] + red[6] + red[7];
  float mean = s * (1.f / NE);
  float var  = sq * (1.f / NE) - mean * mean;
  float rs = rsqrtf(var + 1e-5f);
  u16* orow = out + (long)row * NE;
#pragma unroll
  for (int i = 0; i < 3; ++i){
    int c = t + i * 256;
    orow[c] = f2bf((v[i] - mean) * rs * g[c] + b[c]);
  }
}

// ---------------- barrier-free fused causal flash attention ----------------
// qkv: [TT][2304] bf16 (Q cols [0,768), K cols [768,1536); V unused here)
// vt:  [24][64][1024] bf16 (V^T per bh, produced by qkv GEMM epilogue)
// out: [TT][768] bf16
// grid (24 bh, 16 q-tiles of 64); 4 waves; wave owns 16 q rows. No __syncthreads.
__global__ __launch_bounds__(256) void k_flash(const u16* __restrict__ qkv,
    const u16* __restrict__ vt, u16* __restrict__ out){
  __shared__ u16 Ps[4][16][72];          // wave-private P tile (q x kv)
  const int z = blockIdx.x, qt = blockIdx.y;
  const int b = z / NH, h = z % NH;
  const int q0 = qt * 64;
  const int t = threadIdx.x, lane = t & 63, wid = t >> 6;
  const int lr = lane & 15, lk = lane >> 4;
  const int qr0 = q0 + wid * 16;         // wave's first q row
  // Q fragments (registers, loaded once)
  const u16* Qp = qkv + (long)(b * SL + qr0 + lr) * QKVD + h * HD;
  short8 aq[2];
  aq[0] = *(const short8*)(Qp + lk * 8);
  aq[1] = *(const short8*)(Qp + 32 + lk * 8);
  const u16* Kb  = qkv + (long)(b * SL) * QKVD + NE + h * HD;
  const u16* Vtb = vt + (long)z * HD * SL;
  f32x4 o[4] = {};
  float m[4], l[4];
#pragma unroll
  for (int r = 0; r < 4; ++r){ m[r] = -3e38f; l[r] = 0.f; }
  const int nt = qt + 1;
  for (int kt = 0; kt < nt; ++kt){
    const int kv0 = kt * 64;
    // K fragments direct from global (L2-resident)
    short8 kb[4][2];
#pragma unroll
    for (int j = 0; j < 4; ++j)
#pragma unroll
      for (int c = 0; c < 2; ++c)
        kb[j][c] = *(const short8*)(Kb + (long)(kv0 + j * 16 + lr) * QKVD + c * 32 + lk * 8);
    f32x4 s[4] = {};
#pragma unroll
    for (int c = 0; c < 2; ++c)
#pragma unroll
      for (int j = 0; j < 4; ++j)
        s[j] = __builtin_amdgcn_mfma_f32_16x16x32_bf16(aq[c], kb[j][c], s[j], 0, 0, 0);
    const bool dm = (kt == nt - 1);      // only the diagonal tile needs masking
#pragma unroll
    for (int r = 0; r < 4; ++r){
      const int row = qr0 + lk * 4 + r;
      float pm = -3e38f;
#pragma unroll
      for (int j = 0; j < 4; ++j){
        float v = s[j][r] * 0.125f;
        if (dm && (kv0 + j * 16 + lr > row)) v = -3e38f;
        s[j][r] = v;
        pm = fmaxf(pm, v);
      }
#pragma unroll
      for (int off = 1; off < 16; off <<= 1) pm = fmaxf(pm, __shfl_xor(pm, off));
      float mn = fmaxf(m[r], pm);
      float f = __expf(m[r] - mn);
      m[r] = mn;
      float ps = 0.f;
#pragma unroll
      for (int j = 0; j < 4; ++j){
        float pv = __expf(s[j][r] - mn);
        ps += pv;
        Ps[wid][lk * 4 + r][j * 16 + lr] = f2bf(pv);
      }
#pragma unroll
      for (int off = 1; off < 16; off <<= 1) ps += __shfl_xor(ps, off);
      l[r] = l[r] * f + ps;
#pragma unroll
      for (int j = 0; j < 4; ++j) o[j][r] *= f;
    }
    // O += P V : A-frag from wave-private LDS, B-frag direct from vt (L2)
#pragma unroll
    for (int c = 0; c < 2; ++c){
      short8 pa = *(const short8*)&Ps[wid][lr][c * 32 + lk * 8];
#pragma unroll
      for (int j = 0; j < 4; ++j){
        short8 vb = *(const short8*)(Vtb + (long)(j * 16 + lr) * SL + kv0 + c * 32 + lk * 8);
        o[j] = __builtin_amdgcn_mfma_f32_16x16x32_bf16(pa, vb, o[j], 0, 0, 0);
      }
    }
  }
  u16* O = out + (long)(b * SL) * NE + h * HD;
#pragma unroll
  for (int r = 0; r < 4; ++r){
    float inv = 1.f / l[r];
    const int row = qr0 + lk * 4 + r;
#pragma unroll
    for (int j = 0; j < 4; ++j)
      O[(long)row * NE + j * 16 + lr] = f2bf(o[j][r] * inv);
  }
}

// ---------------- generic bf16 MFMA GEMM, B^T layout (m97 structure) ----------------
// modes: 2 bf16 +bias +gelu(erf), 3 f32 raw, 5 qkv: bf16 +bias, V cols scattered to vt
struct GemmP {
  const u16* A; const u16* B; void* C;
  const float* bias; u16* vt;
  int M, N, K, lda, ldb, ldc, mode;
  long zA, zB, zC;                       // per-blockIdx.z element offsets (split-K)
};

__global__ __launch_bounds__(256) void k_gemm_bt(GemmP p){
  __shared__ u16 As[128 * 32];
  __shared__ u16 Bs[128 * 32];
  const int m0 = blockIdx.x * 128, n0 = blockIdx.y * 128;
  const u16* A = p.A + (long)blockIdx.z * p.zA;
  const u16* B = p.B + (long)blockIdx.z * p.zB;
  const long offC = (long)blockIdx.z * p.zC;
  const int t = threadIdx.x, lane = t & 63, wid = t >> 6;
  const int wm = (wid >> 1) * 64, wn = (wid & 1) * 64;
  const int lr = lane & 15, lk = lane >> 4;
  const int srow0 = wid * 32 + (lane >> 2);
  const int sseg  = (lane & 3) * 8;
  f32x4 acc[4][4] = {};
  for (int k0 = 0; k0 < p.K; k0 += 32){
    const u16* Ab = A + (long)(m0 + srow0) * p.lda + k0 + sseg;
    const u16* Bb = B + (long)(n0 + srow0) * p.ldb + k0 + sseg;
    gload16(Ab, As + (wid * 2 + 0) * 512);
    gload16(Ab + 16 * p.lda, As + (wid * 2 + 1) * 512);
    gload16(Bb, Bs + (wid * 2 + 0) * 512);
    gload16(Bb + 16 * p.ldb, Bs + (wid * 2 + 1) * 512);
    __syncthreads();
    short8 af[4], bfr[4];
#pragma unroll
    for (int i = 0; i < 4; ++i) af[i]  = *(const short8*)&As[(wm + i * 16 + lr) * 32 + lk * 8];
#pragma unroll
    for (int j = 0; j < 4; ++j) bfr[j] = *(const short8*)&Bs[(wn + j * 16 + lr) * 32 + lk * 8];
#pragma unroll
    for (int i = 0; i < 4; ++i)
#pragma unroll
      for (int j = 0; j < 4; ++j)
        acc[i][j] = __builtin_amdgcn_mfma_f32_16x16x32_bf16(af[i], bfr[j], acc[i][j], 0, 0, 0);
    __syncthreads();
  }
#pragma unroll
  for (int i = 0; i < 4; ++i){
#pragma unroll
    for (int r = 0; r < 4; ++r){
      int row = m0 + wm + i * 16 + lk * 4 + r;
      if (row >= p.M) continue;
#pragma unroll
      for (int j = 0; j < 4; ++j){
        int col = n0 + wn + j * 16 + lr;
        if (col >= p.N) continue;
        float v = acc[i][j][r];
        long idx = offC + (long)row * p.ldc + col;
        if (p.mode == 5){
          v += p.bias[col];
          if (col >= 2 * NE){
            int d = col - 2 * NE;                       // head h2 = d>>6, dim dd = d&63
            long vidx = (((long)(row >> 10) * NH + (d >> 6)) * HD + (d & 63)) * SL + (row & 1023);
            p.vt[vidx] = f2bf(v);
          } else {
            ((u16*)p.C)[idx] = f2bf(v);
          }
        } else if (p.mode == 2){
          v += p.bias[col];
          v = 0.5f * v * (1.f + erff(v * 0.70710678118f));
          ((u16*)p.C)[idx] = f2bf(v);
        } else {
          ((float*)p.C)[idx] = v;
        }
      }
    }
  }
}

// -------- split-K combine: h += bias + sum_s part[s]  (float4) --------
__global__ __launch_bounds__(256) void k_combine(float* __restrict__ h,
    const float* __restrict__ part, const float* __restrict__ bias, int nsplit){
  int i = blockIdx.x * 256 + threadIdx.x;          // float4 index, total TT*NE/4
  float4 acc = ((const float4*)h)[i];
  int col4 = (i % (NE / 4)) * 4;
  float4 bb = *(const float4*)(bias + col4);
  acc.x += bb.x; acc.y += bb.y; acc.z += bb.z; acc.w += bb.w;
  for (int s = 0; s < nsplit; ++s){
    float4 pv = ((const float4*)part)[(long)s * (TT * NE / 4) + i];
    acc.x += pv.x; acc.y += pv.y; acc.z += pv.z; acc.w += pv.w;
  }
  ((float4*)h)[i] = acc;
}

static inline void gemm(hipStream_t s, const u16* A, int lda, const u16* B, int ldb,
    void* C, int ldc, int M, int N, int K, const float* bias, u16* vt, int mode,
    int gz = 1, long zA = 0, long zB = 0, long zC = 0){
  GemmP p{ A, B, C, bias, vt, M, N, K, lda, ldb, ldc, mode, zA, zB, zC };
  dim3 g(M / 128, (N + 127) / 128, gz);
  k_gemm_bt<<<g, 256, 0, s>>>(p);
}

extern "C" void kernel_launch(void* const* d_in, const int* in_sizes, int n_in,
                              void* d_out, int out_size, void* d_ws, size_t ws_size,
                              hipStream_t stream){
  (void)in_sizes; (void)n_in; (void)out_size; (void)ws_size;
  const float* x    = (const float*)d_in[0];
  const float* Wqkv = (const float*)d_in[1];
  const float* bqkv = (const float*)d_in[2];
  const float* Wo   = (const float*)d_in[3];
  const float* bo   = (const float*)d_in[4];
  const float* W1   = (const float*)d_in[5];
  const float* b1   = (const float*)d_in[6];
  const float* W2   = (const float*)d_in[7];
  const float* b2   = (const float*)d_in[8];
  const float* ln1g = (const float*)d_in[9];
  const float* ln1b = (const float*)d_in[10];
  const float* ln2g = (const float*)d_in[11];
  const float* ln2b = (const float*)d_in[12];
  const float* lnfg = (const float*)d_in[13];
  const float* lnfb = (const float*)d_in[14];
  const float* Wlm  = (const float*)d_in[15];

  char* ws = (char*)d_ws;
  size_t off = 0;
  auto alloc = [&](size_t bytes){ void* p = ws + off; off += (bytes + 255) & ~255UL; return p; };
  float* h      = (float*)alloc((size_t)TT * NE * 4);
  u16*   a      = (u16*)  alloc((size_t)TT * NE * 2);
  u16*   qkv    = (u16*)  alloc((size_t)TT * QKVD * 2);
  u16*   vtbuf  = (u16*)  alloc((size_t)NB * NH * HD * SL * 2);
  u16*   attno  = (u16*)  alloc((size_t)TT * NE * 2);
  u16*   ffm    = (u16*)  alloc((size_t)TT * DFF * 2);
  float* part   = (float*)alloc((size_t)4 * TT * NE * 4);
  u16*   wqkvT  = (u16*)  alloc((size_t)NL * QKVD * NE * 2);
  u16*   woT    = (u16*)  alloc((size_t)NL * NE * NE * 2);
  u16*   w1T    = (u16*)  alloc((size_t)NL * DFF * NE * 2);
  u16*   w2T    = (u16*)  alloc((size_t)NL * NE * DFF * 2);
  u16*   wlmB   = (u16*)  alloc((size_t)NVP * NE * 2);

  // h = x
  hipMemcpyAsync(h, x, (size_t)TT * NE * 4, hipMemcpyDeviceToDevice, stream);
  // weight conversions
  k_transpose_cvt_all<<<dim3(QKVD / 32, NE / 32, NL), 256, 0, stream>>>(Wqkv, wqkvT, NE, QKVD);
  k_transpose_cvt_all<<<dim3(NE / 32, NE / 32, NL),   256, 0, stream>>>(Wo,   woT,   NE, NE);
  k_transpose_cvt_all<<<dim3(DFF / 32, NE / 32, NL),  256, 0, stream>>>(W1,   w1T,   NE, DFF);
  k_transpose_cvt_all<<<dim3(NE / 32, DFF / 32, NL),  256, 0, stream>>>(W2,   w2T,   DFF, NE);
  k_cvt4<<<2048, 256, 0, stream>>>((const float4*)Wlm, (u16x4*)wlmB, (long)NV * NE / 4);
  hipMemsetAsync(wlmB + (size_t)NV * NE, 0, (size_t)(NVP - NV) * NE * 2, stream);

  for (int L = 0; L < NL; ++L){
    // ln1 -> a
    k_layernorm<<<TT, 256, 0, stream>>>(h, ln1g + L * NE, ln1b + L * NE, a);
    // qkv = a @ Wqkv + bqkv ; V columns scattered transposed into vtbuf
    gemm(stream, a, NE, wqkvT + (size_t)L * QKVD * NE, NE, qkv, QKVD, TT, QKVD, NE,
         bqkv + (size_t)L * QKVD, vtbuf, 5);
    // fused causal attention -> attno
    k_flash<<<dim3(NB * NH, SL / 64), 256, 0, stream>>>(qkv, vtbuf, attno);
    // proj: split-K x2 partials, then h += bo + sum
    gemm(stream, attno, NE, woT + (size_t)L * NE * NE, NE, part, NE, TT, NE, 384,
         nullptr, nullptr, 3, 2, 384, 384, (long)TT * NE);
    k_combine<<<TT * NE / 1024, 256, 0, stream>>>(h, part, bo + (size_t)L * NE, 2);
    // ln2 -> a
    k_layernorm<<<TT, 256, 0, stream>>>(h, ln2g + L * NE, ln2b + L * NE, a);
    // ffm = gelu(a @ W1 + b1)
    gemm(stream, a, NE, w1T + (size_t)L * DFF * NE, NE, ffm, DFF, TT, DFF, NE,
         b1 + (size_t)L * DFF, nullptr, 2);
    // ff2: split-K x4 partials, then h += b2 + sum
    gemm(stream, ffm, DFF, w2T + (size_t)L * NE * DFF, DFF, part, NE, TT, NE, 768,
         nullptr, nullptr, 3, 4, 768, 768, (long)TT * NE);
    k_combine<<<TT * NE / 1024, 256, 0, stream>>>(h, part, b2 + (size_t)L * NE, 4);
  }
  // final LN -> a
  k_layernorm<<<TT, 256, 0, stream>>>(h, lnfg, lnfb, a);
  // logits = a @ Wlm^T  (f32 out)
  gemm(stream, a, NE, wlmB, NE, d_out, NV, TT, NV, NE, nullptr, nullptr, 3);
}

// Round 5
// 2875.899 us; speedup vs baseline: 1.7357x; 1.0252x over previous
//
#include <hip/hip_runtime.h>
#include <math.h>

typedef unsigned short u16;
typedef u16 u16x8 __attribute__((ext_vector_type(8)));
typedef u16 u16x4 __attribute__((ext_vector_type(4)));
typedef short short8 __attribute__((ext_vector_type(8)));
typedef float f32x4 __attribute__((ext_vector_type(4)));

#define NE 768
#define NH 12
#define NL 12
#define NV 50257
#define NVP 50304   // NV padded to 128 multiple for unguarded B staging
#define HD 64
#define DFF 3072
#define NB 2
#define SL 1024
#define TT 2048     // NB*SL tokens
#define QKVD 2304   // 3*NE

static __device__ __forceinline__ u16 f2bf(float f){
  unsigned int x; __builtin_memcpy(&x, &f, 4);
  x = (x + 0x7FFFu + ((x >> 16) & 1u)) >> 16;
  return (u16)x;
}

typedef const __attribute__((address_space(1))) unsigned int* gas1_t;
typedef __attribute__((address_space(3))) unsigned int* las3_t;
static __device__ __forceinline__ void gload16(const u16* g, u16* l){
  __builtin_amdgcn_global_load_lds((gas1_t)(const void*)g, (las3_t)(void*)l, 16, 0, 0);
}

// ---------------- fp32 -> bf16 convert (vectorized) ----------------
__global__ void k_cvt4(const float4* __restrict__ in, u16x4* __restrict__ out, long n4){
  long i = (long)blockIdx.x * blockDim.x + threadIdx.x;
  long st = (long)gridDim.x * blockDim.x;
  for (; i < n4; i += st){
    float4 v = in[i];
    u16x4 o = { f2bf(v.x), f2bf(v.y), f2bf(v.z), f2bf(v.w) };
    out[i] = o;
  }
}

// ------ fp32 [L][K][N] -> bf16 [L][N][K] transpose-convert, all layers ------
__global__ __launch_bounds__(256) void k_transpose_cvt_all(const float* __restrict__ in0,
    u16* __restrict__ out0, int K, int N){
  __shared__ u16 tile[32][33];
  const float* in = in0 + (long)blockIdx.z * K * N;
  u16* out = out0 + (long)blockIdx.z * N * K;
  int n0 = blockIdx.x * 32, k0 = blockIdx.y * 32;
#pragma unroll
  for (int i = 0; i < 4; ++i){
    int e = threadIdx.x + i * 256;
    int r = e >> 5, c = e & 31;          // r: k, c: n
    tile[r][c] = f2bf(in[(long)(k0 + r) * N + (n0 + c)]);
  }
  __syncthreads();
#pragma unroll
  for (int i = 0; i < 4; ++i){
    int e = threadIdx.x + i * 256;
    int r = e >> 5, c = e & 31;          // r: n, c: k
    out[(long)(n0 + r) * K + (k0 + c)] = tile[c][r];
  }
}

// ---------------- LayerNorm: f32 [TT][768] -> bf16 ----------------
__global__ __launch_bounds__(256) void k_layernorm(const float* __restrict__ x,
    const float* __restrict__ g, const float* __restrict__ b, u16* __restrict__ out){
  int row = blockIdx.x;
  const float* xr = x + (long)row * NE;
  int t = threadIdx.x;
  float v[3];
  v[0] = xr[t]; v[1] = xr[t + 256]; v[2] = xr[t + 512];
  float s = v[0] + v[1] + v[2];
  float sq = v[0]*v[0] + v[1]*v[1] + v[2]*v[2];
  __shared__ float red[8];
#pragma unroll
  for (int o = 32; o; o >>= 1){ s += __shfl_xor(s, o); sq += __shfl_xor(sq, o); }
  int wid = t >> 6, lane = t & 63;
  if (!lane){ red[wid] = s; red[4 + wid] = sq; }
  __syncthreads();
  s  = red[0] + red[1] + red[2] + red[3];
  sq = red[4] + red[5] + red[6] + red[7];
  float mean = s * (1.f / NE);
  float var  = sq * (1.f / NE) - mean * mean;
  float rs = rsqrtf(var + 1e-5f);
  u16* orow = out + (long)row * NE;
#pragma unroll
  for (int i = 0; i < 3; ++i){
    int c = t + i * 256;
    orow[c] = f2bf((v[i] - mean) * rs * g[c] + b[c]);
  }
}

// ---- split-K combine + LayerNorm fused: one block per token row ----
// h[row] += bias + sum_s part[s][row]; a[row] = LN(h[row]; g,b)
__global__ __launch_bounds__(256) void k_combine_ln(float* __restrict__ h,
    const float* __restrict__ part, const float* __restrict__ bias, int nsplit,
    const float* __restrict__ g, const float* __restrict__ b, u16* __restrict__ aout){
  int row = blockIdx.x;
  int t = threadIdx.x;
  float* hr = h + (long)row * NE;
  float v[3];
#pragma unroll
  for (int i = 0; i < 3; ++i){
    int c = t + i * 256;
    float acc = hr[c] + bias[c];
    for (int s = 0; s < nsplit; ++s)
      acc += part[(long)s * TT * NE + (long)row * NE + c];
    v[i] = acc;
    hr[c] = acc;
  }
  float s = v[0] + v[1] + v[2];
  float sq = v[0]*v[0] + v[1]*v[1] + v[2]*v[2];
  __shared__ float red[8];
#pragma unroll
  for (int o = 32; o; o >>= 1){ s += __shfl_xor(s, o); sq += __shfl_xor(sq, o); }
  int wid = t >> 6, lane = t & 63;
  if (!lane){ red[wid] = s; red[4 + wid] = sq; }
  __syncthreads();
  s  = red[0] + red[1] + red[2] + red[3];
  sq = red[4] + red[5] + red[6] + red[7];
  float mean = s * (1.f / NE);
  float var  = sq * (1.f / NE) - mean * mean;
  float rs = rsqrtf(var + 1e-5f);
  u16* orow = aout + (long)row * NE;
#pragma unroll
  for (int i = 0; i < 3; ++i){
    int c = t + i * 256;
    orow[c] = f2bf((v[i] - mean) * rs * g[c] + b[c]);
  }
}

// ---------------- barrier-free fused causal flash attention ----------------
__global__ __launch_bounds__(256) void k_flash(const u16* __restrict__ qkv,
    const u16* __restrict__ vt, u16* __restrict__ out){
  __shared__ u16 Ps[4][16][72];          // wave-private P tile (q x kv)
  const int z = blockIdx.x, qt = blockIdx.y;
  const int b = z / NH, h = z % NH;
  const int q0 = qt * 64;
  const int t = threadIdx.x, lane = t & 63, wid = t >> 6;
  const int lr = lane & 15, lk = lane >> 4;
  const int qr0 = q0 + wid * 16;         // wave's first q row
  const u16* Qp = qkv + (long)(b * SL + qr0 + lr) * QKVD + h * HD;
  short8 aq[2];
  aq[0] = *(const short8*)(Qp + lk * 8);
  aq[1] = *(const short8*)(Qp + 32 + lk * 8);
  const u16* Kb  = qkv + (long)(b * SL) * QKVD + NE + h * HD;
  const u16* Vtb = vt + (long)z * HD * SL;
  f32x4 o[4] = {};
  float m[4], l[4];
#pragma unroll
  for (int r = 0; r < 4; ++r){ m[r] = -3e38f; l[r] = 0.f; }
  const int nt = qt + 1;
  for (int kt = 0; kt < nt; ++kt){
    const int kv0 = kt * 64;
    short8 kb[4][2];
#pragma unroll
    for (int j = 0; j < 4; ++j)
#pragma unroll
      for (int c = 0; c < 2; ++c)
        kb[j][c] = *(const short8*)(Kb + (long)(kv0 + j * 16 + lr) * QKVD + c * 32 + lk * 8);
    f32x4 s[4] = {};
#pragma unroll
    for (int c = 0; c < 2; ++c)
#pragma unroll
      for (int j = 0; j < 4; ++j)
        s[j] = __builtin_amdgcn_mfma_f32_16x16x32_bf16(aq[c], kb[j][c], s[j], 0, 0, 0);
    const bool dm = (kt == nt - 1);
#pragma unroll
    for (int r = 0; r < 4; ++r){
      const int row = qr0 + lk * 4 + r;
      float pm = -3e38f;
#pragma unroll
      for (int j = 0; j < 4; ++j){
        float v = s[j][r] * 0.125f;
        if (dm && (kv0 + j * 16 + lr > row)) v = -3e38f;
        s[j][r] = v;
        pm = fmaxf(pm, v);
      }
#pragma unroll
      for (int off = 1; off < 16; off <<= 1) pm = fmaxf(pm, __shfl_xor(pm, off));
      float mn = fmaxf(m[r], pm);
      float f = __expf(m[r] - mn);
      m[r] = mn;
      float ps = 0.f;
#pragma unroll
      for (int j = 0; j < 4; ++j){
        float pv = __expf(s[j][r] - mn);
        ps += pv;
        Ps[wid][lk * 4 + r][j * 16 + lr] = f2bf(pv);
      }
#pragma unroll
      for (int off = 1; off < 16; off <<= 1) ps += __shfl_xor(ps, off);
      l[r] = l[r] * f + ps;
#pragma unroll
      for (int j = 0; j < 4; ++j) o[j][r] *= f;
    }
#pragma unroll
    for (int c = 0; c < 2; ++c){
      short8 pa = *(const short8*)&Ps[wid][lr][c * 32 + lk * 8];
#pragma unroll
      for (int j = 0; j < 4; ++j){
        short8 vb = *(const short8*)(Vtb + (long)(j * 16 + lr) * SL + kv0 + c * 32 + lk * 8);
        o[j] = __builtin_amdgcn_mfma_f32_16x16x32_bf16(pa, vb, o[j], 0, 0, 0);
      }
    }
  }
  u16* O = out + (long)(b * SL) * NE + h * HD;
#pragma unroll
  for (int r = 0; r < 4; ++r){
    float inv = 1.f / l[r];
    const int row = qr0 + lk * 4 + r;
#pragma unroll
    for (int j = 0; j < 4; ++j)
      O[(long)row * NE + j * 16 + lr] = f2bf(o[j][r] * inv);
  }
}

// ------- generic bf16 MFMA GEMM, B^T layout, 2-phase dbuf prefetch -------
// modes: 2 bf16 +bias +gelu(erf), 3 f32 raw, 5 qkv: bf16 +bias, V cols scattered to vt
struct GemmP {
  const u16* A; const u16* B; void* C;
  const float* bias; u16* vt;
  int M, N, K, lda, ldb, ldc, mode;
  long zA, zB, zC;                       // per-blockIdx.z element offsets (split-K)
};

__global__ __launch_bounds__(256) void k_gemm_bt(GemmP p){
  __shared__ u16 As[2][128 * 32];
  __shared__ u16 Bs[2][128 * 32];
  // XCD-aware block swizzle (nwg is always a multiple of 8 here)
  const int nwg = gridDim.x * gridDim.y;
  const int orig = blockIdx.x + blockIdx.y * gridDim.x;
  const int wg = (orig & 7) * (nwg >> 3) + (orig >> 3);
  const int m0 = (wg % gridDim.x) * 128, n0 = (wg / gridDim.x) * 128;
  const u16* A = p.A + (long)blockIdx.z * p.zA;
  const u16* B = p.B + (long)blockIdx.z * p.zB;
  const long offC = (long)blockIdx.z * p.zC;
  const int t = threadIdx.x, lane = t & 63, wid = t >> 6;
  const int wm = (wid >> 1) * 64, wn = (wid & 1) * 64;
  const int lr = lane & 15, lk = lane >> 4;
  const int srow0 = wid * 32 + (lane >> 2);
  const int sseg  = (lane & 3) * 8;
  const u16* Abase = A + (long)(m0 + srow0) * p.lda + sseg;
  const u16* Bbase = B + (long)(n0 + srow0) * p.ldb + sseg;
  auto stage = [&](int buf, int kt){
    const u16* Ab = Abase + kt * 32;
    const u16* Bb = Bbase + kt * 32;
    gload16(Ab,              &As[buf][(wid * 2 + 0) * 512]);
    gload16(Ab + 16 * p.lda, &As[buf][(wid * 2 + 1) * 512]);
    gload16(Bb,              &Bs[buf][(wid * 2 + 0) * 512]);
    gload16(Bb + 16 * p.ldb, &Bs[buf][(wid * 2 + 1) * 512]);
  };
  f32x4 acc[4][4] = {};
  const int nk = p.K >> 5;
  stage(0, 0);
  __syncthreads();
  for (int kt = 0; kt < nk; ++kt){
    const int cur = kt & 1;
    if (kt + 1 < nk) stage(cur ^ 1, kt + 1);   // prefetch overlaps MFMA below
    short8 af[4], bfr[4];
#pragma unroll
    for (int i = 0; i < 4; ++i) af[i]  = *(const short8*)&As[cur][(wm + i * 16 + lr) * 32 + lk * 8];
#pragma unroll
    for (int j = 0; j < 4; ++j) bfr[j] = *(const short8*)&Bs[cur][(wn + j * 16 + lr) * 32 + lk * 8];
#pragma unroll
    for (int i = 0; i < 4; ++i)
#pragma unroll
      for (int j = 0; j < 4; ++j)
        acc[i][j] = __builtin_amdgcn_mfma_f32_16x16x32_bf16(af[i], bfr[j], acc[i][j], 0, 0, 0);
    __syncthreads();   // drains prefetch vmcnt + guards buffer reuse
  }
#pragma unroll
  for (int i = 0; i < 4; ++i){
#pragma unroll
    for (int r = 0; r < 4; ++r){
      int row = m0 + wm + i * 16 + lk * 4 + r;
      if (row >= p.M) continue;
#pragma unroll
      for (int j = 0; j < 4; ++j){
        int col = n0 + wn + j * 16 + lr;
        if (col >= p.N) continue;
        float v = acc[i][j][r];
        long idx = offC + (long)row * p.ldc + col;
        if (p.mode == 5){
          v += p.bias[col];
          if (col >= 2 * NE){
            int d = col - 2 * NE;
            long vidx = (((long)(row >> 10) * NH + (d >> 6)) * HD + (d & 63)) * SL + (row & 1023);
            p.vt[vidx] = f2bf(v);
          } else {
            ((u16*)p.C)[idx] = f2bf(v);
          }
        } else if (p.mode == 2){
          v += p.bias[col];
          v = 0.5f * v * (1.f + erff(v * 0.70710678118f));
          ((u16*)p.C)[idx] = f2bf(v);
        } else {
          ((float*)p.C)[idx] = v;
        }
      }
    }
  }
}

static inline void gemm(hipStream_t s, const u16* A, int lda, const u16* B, int ldb,
    void* C, int ldc, int M, int N, int K, const float* bias, u16* vt, int mode,
    int gz = 1, long zA = 0, long zB = 0, long zC = 0){
  GemmP p{ A, B, C, bias, vt, M, N, K, lda, ldb, ldc, mode, zA, zB, zC };
  dim3 g(M / 128, (N + 127) / 128, gz);
  k_gemm_bt<<<g, 256, 0, s>>>(p);
}

extern "C" void kernel_launch(void* const* d_in, const int* in_sizes, int n_in,
                              void* d_out, int out_size, void* d_ws, size_t ws_size,
                              hipStream_t stream){
  (void)in_sizes; (void)n_in; (void)out_size; (void)ws_size;
  const float* x    = (const float*)d_in[0];
  const float* Wqkv = (const float*)d_in[1];
  const float* bqkv = (const float*)d_in[2];
  const float* Wo   = (const float*)d_in[3];
  const float* bo   = (const float*)d_in[4];
  const float* W1   = (const float*)d_in[5];
  const float* b1   = (const float*)d_in[6];
  const float* W2   = (const float*)d_in[7];
  const float* b2   = (const float*)d_in[8];
  const float* ln1g = (const float*)d_in[9];
  const float* ln1b = (const float*)d_in[10];
  const float* ln2g = (const float*)d_in[11];
  const float* ln2b = (const float*)d_in[12];
  const float* lnfg = (const float*)d_in[13];
  const float* lnfb = (const float*)d_in[14];
  const float* Wlm  = (const float*)d_in[15];

  char* ws = (char*)d_ws;
  size_t off = 0;
  auto alloc = [&](size_t bytes){ void* p = ws + off; off += (bytes + 255) & ~255UL; return p; };
  float* h      = (float*)alloc((size_t)TT * NE * 4);
  u16*   a      = (u16*)  alloc((size_t)TT * NE * 2);
  u16*   qkv    = (u16*)  alloc((size_t)TT * QKVD * 2);
  u16*   vtbuf  = (u16*)  alloc((size_t)NB * NH * HD * SL * 2);
  u16*   attno  = (u16*)  alloc((size_t)TT * NE * 2);
  u16*   ffm    = (u16*)  alloc((size_t)TT * DFF * 2);
  float* part   = (float*)alloc((size_t)4 * TT * NE * 4);
  u16*   wqkvT  = (u16*)  alloc((size_t)NL * QKVD * NE * 2);
  u16*   woT    = (u16*)  alloc((size_t)NL * NE * NE * 2);
  u16*   w1T    = (u16*)  alloc((size_t)NL * DFF * NE * 2);
  u16*   w2T    = (u16*)  alloc((size_t)NL * NE * DFF * 2);
  u16*   wlmB   = (u16*)  alloc((size_t)NVP * NE * 2);

  // h = x
  hipMemcpyAsync(h, x, (size_t)TT * NE * 4, hipMemcpyDeviceToDevice, stream);
  // weight conversions
  k_transpose_cvt_all<<<dim3(QKVD / 32, NE / 32, NL), 256, 0, stream>>>(Wqkv, wqkvT, NE, QKVD);
  k_transpose_cvt_all<<<dim3(NE / 32, NE / 32, NL),   256, 0, stream>>>(Wo,   woT,   NE, NE);
  k_transpose_cvt_all<<<dim3(DFF / 32, NE / 32, NL),  256, 0, stream>>>(W1,   w1T,   NE, DFF);
  k_transpose_cvt_all<<<dim3(NE / 32, DFF / 32, NL),  256, 0, stream>>>(W2,   w2T,   DFF, NE);
  k_cvt4<<<2048, 256, 0, stream>>>((const float4*)Wlm, (u16x4*)wlmB, (long)NV * NE / 4);
  hipMemsetAsync(wlmB + (size_t)NV * NE, 0, (size_t)(NVP - NV) * NE * 2, stream);

  // ln1 of layer 0
  k_layernorm<<<TT, 256, 0, stream>>>(h, ln1g, ln1b, a);

  for (int L = 0; L < NL; ++L){
    // qkv = a @ Wqkv + bqkv ; V columns scattered transposed into vtbuf
    gemm(stream, a, NE, wqkvT + (size_t)L * QKVD * NE, NE, qkv, QKVD, TT, QKVD, NE,
         bqkv + (size_t)L * QKVD, vtbuf, 5);
    // fused causal attention -> attno
    k_flash<<<dim3(NB * NH, SL / 64), 256, 0, stream>>>(qkv, vtbuf, attno);
    // proj: split-K x2 partials
    gemm(stream, attno, NE, woT + (size_t)L * NE * NE, NE, part, NE, TT, NE, 384,
         nullptr, nullptr, 3, 2, 384, 384, (long)TT * NE);
    // h += bo + parts; a = ln2(h)
    k_combine_ln<<<TT, 256, 0, stream>>>(h, part, bo + (size_t)L * NE, 2,
         ln2g + (size_t)L * NE, ln2b + (size_t)L * NE, a);
    // ffm = gelu(a @ W1 + b1)
    gemm(stream, a, NE, w1T + (size_t)L * DFF * NE, NE, ffm, DFF, TT, DFF, NE,
         b1 + (size_t)L * DFF, nullptr, 2);
    // ff2: split-K x4 partials
    gemm(stream, ffm, DFF, w2T + (size_t)L * NE * DFF, DFF, part, NE, TT, NE, 768,
         nullptr, nullptr, 3, 4, 768, 768, (long)TT * NE);
    // h += b2 + parts; a = ln1(next) or lnf (last layer)
    const float* gn = (L + 1 < NL) ? ln1g + (size_t)(L + 1) * NE : lnfg;
    const float* bn = (L + 1 < NL) ? ln1b + (size_t)(L + 1) * NE : lnfb;
    k_combine_ln<<<TT, 256, 0, stream>>>(h, part, b2 + (size_t)L * NE, 4, gn, bn, a);
  }
  // logits = a @ Wlm^T  (f32 out)
  gemm(stream, a, NE, wlmB, NE, d_out, NV, TT, NV, NE, nullptr, nullptr, 3);
}

// Round 7
// 2862.931 us; speedup vs baseline: 1.7435x; 1.0045x over previous
//
#include <hip/hip_runtime.h>
#include <math.h>

typedef unsigned short u16;
typedef u16 u16x8 __attribute__((ext_vector_type(8)));
typedef u16 u16x4 __attribute__((ext_vector_type(4)));
typedef short short8 __attribute__((ext_vector_type(8)));
typedef float f32x4 __attribute__((ext_vector_type(4)));

#define NE 768
#define NH 12
#define NL 12
#define NV 50257
#define NVP 50304   // NV padded to 128 multiple for unguarded B staging
#define HD 64
#define DFF 3072
#define NB 2
#define SL 1024
#define TT 2048     // NB*SL tokens
#define QKVD 2304   // 3*NE

static __device__ __forceinline__ u16 f2bf(float f){
  unsigned int x; __builtin_memcpy(&x, &f, 4);
  x = (x + 0x7FFFu + ((x >> 16) & 1u)) >> 16;
  return (u16)x;
}

typedef const __attribute__((address_space(1))) unsigned int* gas1_t;
typedef __attribute__((address_space(3))) unsigned int* las3_t;
static __device__ __forceinline__ void gload16(const u16* g, u16* l){
  __builtin_amdgcn_global_load_lds((gas1_t)(const void*)g, (las3_t)(void*)l, 16, 0, 0);
}
// counted vmcnt wait: N loads may remain in flight (wave-uniform arg)
static __device__ __forceinline__ void waitvm(int n){
  if (n == 0)      asm volatile("s_waitcnt vmcnt(0)" ::: "memory");
  else if (n == 4) asm volatile("s_waitcnt vmcnt(4)" ::: "memory");
  else             asm volatile("s_waitcnt vmcnt(8)" ::: "memory");
}

// ---------------- fp32 -> bf16 convert (vectorized) ----------------
__global__ void k_cvt4(const float4* __restrict__ in, u16x4* __restrict__ out, long n4){
  long i = (long)blockIdx.x * blockDim.x + threadIdx.x;
  long st = (long)gridDim.x * blockDim.x;
  for (; i < n4; i += st){
    float4 v = in[i];
    u16x4 o = { f2bf(v.x), f2bf(v.y), f2bf(v.z), f2bf(v.w) };
    out[i] = o;
  }
}

// ------ fp32 [L][K][N] -> bf16 [L][N][K] transpose-convert, all layers ------
__global__ __launch_bounds__(256) void k_transpose_cvt_all(const float* __restrict__ in0,
    u16* __restrict__ out0, int K, int N){
  __shared__ u16 tile[32][33];
  const float* in = in0 + (long)blockIdx.z * K * N;
  u16* out = out0 + (long)blockIdx.z * N * K;
  int n0 = blockIdx.x * 32, k0 = blockIdx.y * 32;
#pragma unroll
  for (int i = 0; i < 4; ++i){
    int e = threadIdx.x + i * 256;
    int r = e >> 5, c = e & 31;          // r: k, c: n
    tile[r][c] = f2bf(in[(long)(k0 + r) * N + (n0 + c)]);
  }
  __syncthreads();
#pragma unroll
  for (int i = 0; i < 4; ++i){
    int e = threadIdx.x + i * 256;
    int r = e >> 5, c = e & 31;          // r: n, c: k
    out[(long)(n0 + r) * K + (k0 + c)] = tile[c][r];
  }
}

// ---------------- LayerNorm: f32 [TT][768] -> bf16 ----------------
__global__ __launch_bounds__(256) void k_layernorm(const float* __restrict__ x,
    const float* __restrict__ g, const float* __restrict__ b, u16* __restrict__ out){
  int row = blockIdx.x;
  const float* xr = x + (long)row * NE;
  int t = threadIdx.x;
  float v[3];
  v[0] = xr[t]; v[1] = xr[t + 256]; v[2] = xr[t + 512];
  float s = v[0] + v[1] + v[2];
  float sq = v[0]*v[0] + v[1]*v[1] + v[2]*v[2];
  __shared__ float red[8];
#pragma unroll
  for (int o = 32; o; o >>= 1){ s += __shfl_xor(s, o); sq += __shfl_xor(sq, o); }
  int wid = t >> 6, lane = t & 63;
  if (!lane){ red[wid] = s; red[4 + wid] = sq; }
  __syncthreads();
  s  = red[0] + red[1] + red[2] + red[3];
  sq = red[4] + red[5] + red[6] + red[7];
  float mean = s * (1.f / NE);
  float var  = sq * (1.f / NE) - mean * mean;
  float rs = rsqrtf(var + 1e-5f);
  u16* orow = out + (long)row * NE;
#pragma unroll
  for (int i = 0; i < 3; ++i){
    int c = t + i * 256;
    orow[c] = f2bf((v[i] - mean) * rs * g[c] + b[c]);
  }
}

// ---- split-K combine + LayerNorm fused: one block per token row ----
__global__ __launch_bounds__(256) void k_combine_ln(float* __restrict__ h,
    const float* __restrict__ part, const float* __restrict__ bias, int nsplit,
    const float* __restrict__ g, const float* __restrict__ b, u16* __restrict__ aout){
  int row = blockIdx.x;
  int t = threadIdx.x;
  float* hr = h + (long)row * NE;
  float v[3];
#pragma unroll
  for (int i = 0; i < 3; ++i){
    int c = t + i * 256;
    float acc = hr[c] + bias[c];
    for (int s = 0; s < nsplit; ++s)
      acc += part[(long)s * TT * NE + (long)row * NE + c];
    v[i] = acc;
    hr[c] = acc;
  }
  float s = v[0] + v[1] + v[2];
  float sq = v[0]*v[0] + v[1]*v[1] + v[2]*v[2];
  __shared__ float red[8];
#pragma unroll
  for (int o = 32; o; o >>= 1){ s += __shfl_xor(s, o); sq += __shfl_xor(sq, o); }
  int wid = t >> 6, lane = t & 63;
  if (!lane){ red[wid] = s; red[4 + wid] = sq; }
  __syncthreads();
  s  = red[0] + red[1] + red[2] + red[3];
  sq = red[4] + red[5] + red[6] + red[7];
  float mean = s * (1.f / NE);
  float var  = sq * (1.f / NE) - mean * mean;
  float rs = rsqrtf(var + 1e-5f);
  u16* orow = aout + (long)row * NE;
#pragma unroll
  for (int i = 0; i < 3; ++i){
    int c = t + i * 256;
    orow[c] = f2bf((v[i] - mean) * rs * g[c] + b[c]);
  }
}

// ---------------- barrier-free fused causal flash attention ----------------
__global__ __launch_bounds__(256) void k_flash(const u16* __restrict__ qkv,
    const u16* __restrict__ vt, u16* __restrict__ out){
  __shared__ u16 Ps[4][16][72];          // wave-private P tile (q x kv)
  const int z = blockIdx.x;
  const int qt = gridDim.y - 1 - blockIdx.y;   // heavy q-tiles dispatch first
  const int b = z / NH, h = z % NH;
  const int q0 = qt * 64;
  const int t = threadIdx.x, lane = t & 63, wid = t >> 6;
  const int lr = lane & 15, lk = lane >> 4;
  const int qr0 = q0 + wid * 16;         // wave's first q row
  const u16* Qp = qkv + (long)(b * SL + qr0 + lr) * QKVD + h * HD;
  short8 aq[2];
  aq[0] = *(const short8*)(Qp + lk * 8);
  aq[1] = *(const short8*)(Qp + 32 + lk * 8);
  const u16* Kb  = qkv + (long)(b * SL) * QKVD + NE + h * HD;
  const u16* Vtb = vt + (long)z * HD * SL;
  f32x4 o[4] = {};
  float m[4], l[4];
#pragma unroll
  for (int r = 0; r < 4; ++r){ m[r] = -3e38f; l[r] = 0.f; }
  const int nt = qt + 1;
  for (int kt = 0; kt < nt; ++kt){
    const int kv0 = kt * 64;
    short8 kb[4][2];
#pragma unroll
    for (int j = 0; j < 4; ++j)
#pragma unroll
      for (int c = 0; c < 2; ++c)
        kb[j][c] = *(const short8*)(Kb + (long)(kv0 + j * 16 + lr) * QKVD + c * 32 + lk * 8);
    f32x4 s[4] = {};
#pragma unroll
    for (int c = 0; c < 2; ++c)
#pragma unroll
      for (int j = 0; j < 4; ++j)
        s[j] = __builtin_amdgcn_mfma_f32_16x16x32_bf16(aq[c], kb[j][c], s[j], 0, 0, 0);
    const bool dm = (kt == nt - 1);
#pragma unroll
    for (int r = 0; r < 4; ++r){
      const int row = qr0 + lk * 4 + r;
      float pm = -3e38f;
#pragma unroll
      for (int j = 0; j < 4; ++j){
        float v = s[j][r] * 0.125f;
        if (dm && (kv0 + j * 16 + lr > row)) v = -3e38f;
        s[j][r] = v;
        pm = fmaxf(pm, v);
      }
#pragma unroll
      for (int off = 1; off < 16; off <<= 1) pm = fmaxf(pm, __shfl_xor(pm, off));
      float mn = fmaxf(m[r], pm);
      float f = __expf(m[r] - mn);
      m[r] = mn;
      float ps = 0.f;
#pragma unroll
      for (int j = 0; j < 4; ++j){
        float pv = __expf(s[j][r] - mn);
        ps += pv;
        Ps[wid][lk * 4 + r][j * 16 + lr] = f2bf(pv);
      }
#pragma unroll
      for (int off = 1; off < 16; off <<= 1) ps += __shfl_xor(ps, off);
      l[r] = l[r] * f + ps;
#pragma unroll
      for (int j = 0; j < 4; ++j) o[j][r] *= f;
    }
#pragma unroll
    for (int c = 0; c < 2; ++c){
      short8 pa = *(const short8*)&Ps[wid][lr][c * 32 + lk * 8];
#pragma unroll
      for (int j = 0; j < 4; ++j){
        short8 vb = *(const short8*)(Vtb + (long)(j * 16 + lr) * SL + kv0 + c * 32 + lk * 8);
        o[j] = __builtin_amdgcn_mfma_f32_16x16x32_bf16(pa, vb, o[j], 0, 0, 0);
      }
    }
  }
  u16* O = out + (long)(b * SL) * NE + h * HD;
#pragma unroll
  for (int r = 0; r < 4; ++r){
    float inv = 1.f / l[r];
    const int row = qr0 + lk * 4 + r;
#pragma unroll
    for (int j = 0; j < 4; ++j)
      O[(long)row * NE + j * 16 + lr] = f2bf(o[j][r] * inv);
  }
}

// ------- generic bf16 MFMA GEMM, B^T layout, depth-2 counted-vmcnt pipeline -------
// modes: 2 bf16 +bias +gelu(erf), 3 f32 raw, 5 qkv: bf16 +bias, V cols scattered to vt
struct GemmP {
  const u16* A; const u16* B; void* C;
  const float* bias; u16* vt;
  int M, N, K, lda, ldb, ldc, mode;
  long zA, zB, zC;                       // per-blockIdx.z element offsets (split-K)
};

__global__ __launch_bounds__(256) void k_gemm_bt(GemmP p){
  __shared__ u16 As[3][128 * 32];
  __shared__ u16 Bs[3][128 * 32];
  // XCD-aware block swizzle (nwg is always a multiple of 8 here)
  const int nwg = gridDim.x * gridDim.y;
  const int orig = blockIdx.x + blockIdx.y * gridDim.x;
  const int wg = (orig & 7) * (nwg >> 3) + (orig >> 3);
  const int m0 = (wg % gridDim.x) * 128, n0 = (wg / gridDim.x) * 128;
  const u16* A = p.A + (long)blockIdx.z * p.zA;
  const u16* B = p.B + (long)blockIdx.z * p.zB;
  const long offC = (long)blockIdx.z * p.zC;
  const int t = threadIdx.x, lane = t & 63, wid = t >> 6;
  const int wm = (wid >> 1) * 64, wn = (wid & 1) * 64;
  const int lr = lane & 15, lk = lane >> 4;
  const int srow0 = wid * 32 + (lane >> 2);
  const int sseg  = (lane & 3) * 8;
  const u16* Abase = A + (long)(m0 + srow0) * p.lda + sseg;
  const u16* Bbase = B + (long)(n0 + srow0) * p.ldb + sseg;
  auto stage = [&](int buf, int kt){     // 4 gload_lds per thread per K-tile
    const u16* Ab = Abase + kt * 32;
    const u16* Bb = Bbase + kt * 32;
    gload16(Ab,              &As[buf][(wid * 2 + 0) * 512]);
    gload16(Ab + 16 * p.lda, &As[buf][(wid * 2 + 1) * 512]);
    gload16(Bb,              &Bs[buf][(wid * 2 + 0) * 512]);
    gload16(Bb + 16 * p.ldb, &Bs[buf][(wid * 2 + 1) * 512]);
  };
  f32x4 acc[4][4] = {};
  const int nk = p.K >> 5;               // always >= 2 here
  stage(0, 0);
  stage(1, 1);
  int cur = 0;
  for (int kt = 0; kt < nk; ++kt){
    if (kt + 2 < nk){
      int nxt = cur + 2; if (nxt >= 3) nxt -= 3;   // tile kt+2 -> buf (kt+2)%3
      stage(nxt, kt + 2);
    }
    // wait only this tile's 4 loads; leave up to 8 (tiles kt+1, kt+2) in flight
    int rem = nk - 1 - kt;
    waitvm(rem >= 2 ? 8 : rem == 1 ? 4 : 0);
    __builtin_amdgcn_s_barrier();        // all waves' tile-kt loads complete
    short8 af[4], bfr[4];
#pragma unroll
    for (int i = 0; i < 4; ++i) af[i]  = *(const short8*)&As[cur][(wm + i * 16 + lr) * 32 + lk * 8];
#pragma unroll
    for (int j = 0; j < 4; ++j) bfr[j] = *(const short8*)&Bs[cur][(wn + j * 16 + lr) * 32 + lk * 8];
#pragma unroll
    for (int i = 0; i < 4; ++i)
#pragma unroll
      for (int j = 0; j < 4; ++j)
        acc[i][j] = __builtin_amdgcn_mfma_f32_16x16x32_bf16(af[i], bfr[j], acc[i][j], 0, 0, 0);
    asm volatile("s_waitcnt lgkmcnt(0)" ::: "memory");  // ds_reads of buf done
    __builtin_amdgcn_s_barrier();        // before buf is restaged next iter
    cur = (cur == 2) ? 0 : cur + 1;
  }
#pragma unroll
  for (int i = 0; i < 4; ++i){
#pragma unroll
    for (int r = 0; r < 4; ++r){
      int row = m0 + wm + i * 16 + lk * 4 + r;
      if (row >= p.M) continue;
#pragma unroll
      for (int j = 0; j < 4; ++j){
        int col = n0 + wn + j * 16 + lr;
        if (col >= p.N) continue;
        float v = acc[i][j][r];
        long idx = offC + (long)row * p.ldc + col;
        if (p.mode == 5){
          v += p.bias[col];
          if (col >= 2 * NE){
            int d = col - 2 * NE;
            long vidx = (((long)(row >> 10) * NH + (d >> 6)) * HD + (d & 63)) * SL + (row & 1023);
            p.vt[vidx] = f2bf(v);
          } else {
            ((u16*)p.C)[idx] = f2bf(v);
          }
        } else if (p.mode == 2){
          v += p.bias[col];
          v = 0.5f * v * (1.f + erff(v * 0.70710678118f));
          ((u16*)p.C)[idx] = f2bf(v);
        } else {
          ((float*)p.C)[idx] = v;
        }
      }
    }
  }
}

static inline void gemm(hipStream_t s, const u16* A, int lda, const u16* B, int ldb,
    void* C, int ldc, int M, int N, int K, const float* bias, u16* vt, int mode,
    int gz = 1, long zA = 0, long zB = 0, long zC = 0){
  GemmP p{ A, B, C, bias, vt, M, N, K, lda, ldb, ldc, mode, zA, zB, zC };
  dim3 g(M / 128, (N + 127) / 128, gz);
  k_gemm_bt<<<g, 256, 0, s>>>(p);
}

extern "C" void kernel_launch(void* const* d_in, const int* in_sizes, int n_in,
                              void* d_out, int out_size, void* d_ws, size_t ws_size,
                              hipStream_t stream){
  (void)in_sizes; (void)n_in; (void)out_size; (void)ws_size;
  const float* x    = (const float*)d_in[0];
  const float* Wqkv = (const float*)d_in[1];
  const float* bqkv = (const float*)d_in[2];
  const float* Wo   = (const float*)d_in[3];
  const float* bo   = (const float*)d_in[4];
  const float* W1   = (const float*)d_in[5];
  const float* b1   = (const float*)d_in[6];
  const float* W2   = (const float*)d_in[7];
  const float* b2   = (const float*)d_in[8];
  const float* ln1g = (const float*)d_in[9];
  const float* ln1b = (const float*)d_in[10];
  const float* ln2g = (const float*)d_in[11];
  const float* ln2b = (const float*)d_in[12];
  const float* lnfg = (const float*)d_in[13];
  const float* lnfb = (const float*)d_in[14];
  const float* Wlm  = (const float*)d_in[15];

  char* ws = (char*)d_ws;
  size_t off = 0;
  auto alloc = [&](size_t bytes){ void* p = ws + off; off += (bytes + 255) & ~255UL; return p; };
  float* h      = (float*)alloc((size_t)TT * NE * 4);
  u16*   a      = (u16*)  alloc((size_t)TT * NE * 2);
  u16*   qkv    = (u16*)  alloc((size_t)TT * QKVD * 2);
  u16*   vtbuf  = (u16*)  alloc((size_t)NB * NH * HD * SL * 2);
  u16*   attno  = (u16*)  alloc((size_t)TT * NE * 2);
  u16*   ffm    = (u16*)  alloc((size_t)TT * DFF * 2);
  float* part   = (float*)alloc((size_t)4 * TT * NE * 4);
  u16*   wqkvT  = (u16*)  alloc((size_t)NL * QKVD * NE * 2);
  u16*   woT    = (u16*)  alloc((size_t)NL * NE * NE * 2);
  u16*   w1T    = (u16*)  alloc((size_t)NL * DFF * NE * 2);
  u16*   w2T    = (u16*)  alloc((size_t)NL * NE * DFF * 2);
  u16*   wlmB   = (u16*)  alloc((size_t)NVP * NE * 2);

  // h = x
  hipMemcpyAsync(h, x, (size_t)TT * NE * 4, hipMemcpyDeviceToDevice, stream);
  // weight conversions
  k_transpose_cvt_all<<<dim3(QKVD / 32, NE / 32, NL), 256, 0, stream>>>(Wqkv, wqkvT, NE, QKVD);
  k_transpose_cvt_all<<<dim3(NE / 32, NE / 32, NL),   256, 0, stream>>>(Wo,   woT,   NE, NE);
  k_transpose_cvt_all<<<dim3(DFF / 32, NE / 32, NL),  256, 0, stream>>>(W1,   w1T,   NE, DFF);
  k_transpose_cvt_all<<<dim3(NE / 32, DFF / 32, NL),  256, 0, stream>>>(W2,   w2T,   DFF, NE);
  k_cvt4<<<2048, 256, 0, stream>>>((const float4*)Wlm, (u16x4*)wlmB, (long)NV * NE / 4);
  hipMemsetAsync(wlmB + (size_t)NV * NE, 0, (size_t)(NVP - NV) * NE * 2, stream);

  // ln1 of layer 0
  k_layernorm<<<TT, 256, 0, stream>>>(h, ln1g, ln1b, a);

  for (int L = 0; L < NL; ++L){
    // qkv = a @ Wqkv + bqkv ; V columns scattered transposed into vtbuf
    gemm(stream, a, NE, wqkvT + (size_t)L * QKVD * NE, NE, qkv, QKVD, TT, QKVD, NE,
         bqkv + (size_t)L * QKVD, vtbuf, 5);
    // fused causal attention -> attno
    k_flash<<<dim3(NB * NH, SL / 64), 256, 0, stream>>>(qkv, vtbuf, attno);
    // proj: split-K x2 partials
    gemm(stream, attno, NE, woT + (size_t)L * NE * NE, NE, part, NE, TT, NE, 384,
         nullptr, nullptr, 3, 2, 384, 384, (long)TT * NE);
    // h += bo + parts; a = ln2(h)
    k_combine_ln<<<TT, 256, 0, stream>>>(h, part, bo + (size_t)L * NE, 2,
         ln2g + (size_t)L * NE, ln2b + (size_t)L * NE, a);
    // ffm = gelu(a @ W1 + b1)
    gemm(stream, a, NE, w1T + (size_t)L * DFF * NE, NE, ffm, DFF, TT, DFF, NE,
         b1 + (size_t)L * DFF, nullptr, 2);
    // ff2: split-K x4 partials
    gemm(stream, ffm, DFF, w2T + (size_t)L * NE * DFF, DFF, part, NE, TT, NE, 768,
         nullptr, nullptr, 3, 4, 768, 768, (long)TT * NE);
    // h += b2 + parts; a = ln1(next) or lnf (last layer)
    const float* gn = (L + 1 < NL) ? ln1g + (size_t)(L + 1) * NE : lnfg;
    const float* bn = (L + 1 < NL) ? ln1b + (size_t)(L + 1) * NE : lnfb;
    k_combine_ln<<<TT, 256, 0, stream>>>(h, part, b2 + (size_t)L * NE, 4, gn, bn, a);
  }
  // logits = a @ Wlm^T  (f32 out)
  gemm(stream, a, NE, wlmB, NE, d_out, NV, TT, NV, NE, nullptr, nullptr, 3);
}

// Round 8
// 2833.146 us; speedup vs baseline: 1.7619x; 1.0105x over previous
//
#include <hip/hip_runtime.h>
#include <math.h>

typedef unsigned short u16;
typedef u16 u16x8 __attribute__((ext_vector_type(8)));
typedef u16 u16x4 __attribute__((ext_vector_type(4)));
typedef short short8 __attribute__((ext_vector_type(8)));
typedef float f32x4 __attribute__((ext_vector_type(4)));

#define NE 768
#define NH 12
#define NL 12
#define NV 50257
#define NVP 50432   // NV padded to 256 multiple for the 256^2 LM-head GEMM
#define HD 64
#define DFF 3072
#define NB 2
#define SL 1024
#define TT 2048     // NB*SL tokens
#define QKVD 2304   // 3*NE

static __device__ __forceinline__ u16 f2bf(float f){
  unsigned int x; __builtin_memcpy(&x, &f, 4);
  x = (x + 0x7FFFu + ((x >> 16) & 1u)) >> 16;
  return (u16)x;
}

typedef const __attribute__((address_space(1))) unsigned int* gas1_t;
typedef __attribute__((address_space(3))) unsigned int* las3_t;
static __device__ __forceinline__ void gload16(const u16* g, u16* l){
  __builtin_amdgcn_global_load_lds((gas1_t)(const void*)g, (las3_t)(void*)l, 16, 0, 0);
}
// counted vmcnt wait: N loads may remain in flight (wave-uniform arg)
static __device__ __forceinline__ void waitvm(int n){
  if (n == 0)      asm volatile("s_waitcnt vmcnt(0)" ::: "memory");
  else if (n == 4) asm volatile("s_waitcnt vmcnt(4)" ::: "memory");
  else             asm volatile("s_waitcnt vmcnt(8)" ::: "memory");
}

// ---------------- fp32 -> bf16 convert (vectorized) ----------------
__global__ void k_cvt4(const float4* __restrict__ in, u16x4* __restrict__ out, long n4){
  long i = (long)blockIdx.x * blockDim.x + threadIdx.x;
  long st = (long)gridDim.x * blockDim.x;
  for (; i < n4; i += st){
    float4 v = in[i];
    u16x4 o = { f2bf(v.x), f2bf(v.y), f2bf(v.z), f2bf(v.w) };
    out[i] = o;
  }
}

// ------ fp32 [L][K][N] -> bf16 [L][N][K] transpose-convert, all layers ------
__global__ __launch_bounds__(256) void k_transpose_cvt_all(const float* __restrict__ in0,
    u16* __restrict__ out0, int K, int N){
  __shared__ u16 tile[32][33];
  const float* in = in0 + (long)blockIdx.z * K * N;
  u16* out = out0 + (long)blockIdx.z * N * K;
  int n0 = blockIdx.x * 32, k0 = blockIdx.y * 32;
#pragma unroll
  for (int i = 0; i < 4; ++i){
    int e = threadIdx.x + i * 256;
    int r = e >> 5, c = e & 31;          // r: k, c: n
    tile[r][c] = f2bf(in[(long)(k0 + r) * N + (n0 + c)]);
  }
  __syncthreads();
#pragma unroll
  for (int i = 0; i < 4; ++i){
    int e = threadIdx.x + i * 256;
    int r = e >> 5, c = e & 31;          // r: n, c: k
    out[(long)(n0 + r) * K + (k0 + c)] = tile[c][r];
  }
}

// ---------------- LayerNorm: f32 [TT][768] -> bf16 ----------------
__global__ __launch_bounds__(256) void k_layernorm(const float* __restrict__ x,
    const float* __restrict__ g, const float* __restrict__ b, u16* __restrict__ out){
  int row = blockIdx.x;
  const float* xr = x + (long)row * NE;
  int t = threadIdx.x;
  float v[3];
  v[0] = xr[t]; v[1] = xr[t + 256]; v[2] = xr[t + 512];
  float s = v[0] + v[1] + v[2];
  float sq = v[0]*v[0] + v[1]*v[1] + v[2]*v[2];
  __shared__ float red[8];
#pragma unroll
  for (int o = 32; o; o >>= 1){ s += __shfl_xor(s, o); sq += __shfl_xor(sq, o); }
  int wid = t >> 6, lane = t & 63;
  if (!lane){ red[wid] = s; red[4 + wid] = sq; }
  __syncthreads();
  s  = red[0] + red[1] + red[2] + red[3];
  sq = red[4] + red[5] + red[6] + red[7];
  float mean = s * (1.f / NE);
  float var  = sq * (1.f / NE) - mean * mean;
  float rs = rsqrtf(var + 1e-5f);
  u16* orow = out + (long)row * NE;
#pragma unroll
  for (int i = 0; i < 3; ++i){
    int c = t + i * 256;
    orow[c] = f2bf((v[i] - mean) * rs * g[c] + b[c]);
  }
}

// ---- split-K combine + LayerNorm fused: one block per token row ----
__global__ __launch_bounds__(256) void k_combine_ln(float* __restrict__ h,
    const float* __restrict__ part, const float* __restrict__ bias, int nsplit,
    const float* __restrict__ g, const float* __restrict__ b, u16* __restrict__ aout){
  int row = blockIdx.x;
  int t = threadIdx.x;
  float* hr = h + (long)row * NE;
  float v[3];
#pragma unroll
  for (int i = 0; i < 3; ++i){
    int c = t + i * 256;
    float acc = hr[c] + bias[c];
    for (int s = 0; s < nsplit; ++s)
      acc += part[(long)s * TT * NE + (long)row * NE + c];
    v[i] = acc;
    hr[c] = acc;
  }
  float s = v[0] + v[1] + v[2];
  float sq = v[0]*v[0] + v[1]*v[1] + v[2]*v[2];
  __shared__ float red[8];
#pragma unroll
  for (int o = 32; o; o >>= 1){ s += __shfl_xor(s, o); sq += __shfl_xor(sq, o); }
  int wid = t >> 6, lane = t & 63;
  if (!lane){ red[wid] = s; red[4 + wid] = sq; }
  __syncthreads();
  s  = red[0] + red[1] + red[2] + red[3];
  sq = red[4] + red[5] + red[6] + red[7];
  float mean = s * (1.f / NE);
  float var  = sq * (1.f / NE) - mean * mean;
  float rs = rsqrtf(var + 1e-5f);
  u16* orow = aout + (long)row * NE;
#pragma unroll
  for (int i = 0; i < 3; ++i){
    int c = t + i * 256;
    orow[c] = f2bf((v[i] - mean) * rs * g[c] + b[c]);
  }
}

// ---------------- barrier-free fused causal flash attention ----------------
__global__ __launch_bounds__(256) void k_flash(const u16* __restrict__ qkv,
    const u16* __restrict__ vt, u16* __restrict__ out){
  __shared__ u16 Ps[4][16][72];          // wave-private P tile (q x kv)
  const int z = blockIdx.x;
  const int qt = gridDim.y - 1 - blockIdx.y;   // heavy q-tiles dispatch first
  const int b = z / NH, h = z % NH;
  const int q0 = qt * 64;
  const int t = threadIdx.x, lane = t & 63, wid = t >> 6;
  const int lr = lane & 15, lk = lane >> 4;
  const int qr0 = q0 + wid * 16;         // wave's first q row
  const u16* Qp = qkv + (long)(b * SL + qr0 + lr) * QKVD + h * HD;
  short8 aq[2];
  aq[0] = *(const short8*)(Qp + lk * 8);
  aq[1] = *(const short8*)(Qp + 32 + lk * 8);
  const u16* Kb  = qkv + (long)(b * SL) * QKVD + NE + h * HD;
  const u16* Vtb = vt + (long)z * HD * SL;
  f32x4 o[4] = {};
  float m[4], l[4];
#pragma unroll
  for (int r = 0; r < 4; ++r){ m[r] = -3e38f; l[r] = 0.f; }
  const int nt = qt + 1;
  for (int kt = 0; kt < nt; ++kt){
    const int kv0 = kt * 64;
    short8 kb[4][2];
#pragma unroll
    for (int j = 0; j < 4; ++j)
#pragma unroll
      for (int c = 0; c < 2; ++c)
        kb[j][c] = *(const short8*)(Kb + (long)(kv0 + j * 16 + lr) * QKVD + c * 32 + lk * 8);
    f32x4 s[4] = {};
#pragma unroll
    for (int c = 0; c < 2; ++c)
#pragma unroll
      for (int j = 0; j < 4; ++j)
        s[j] = __builtin_amdgcn_mfma_f32_16x16x32_bf16(aq[c], kb[j][c], s[j], 0, 0, 0);
    const bool dm = (kt == nt - 1);
#pragma unroll
    for (int r = 0; r < 4; ++r){
      const int row = qr0 + lk * 4 + r;
      float pm = -3e38f;
#pragma unroll
      for (int j = 0; j < 4; ++j){
        float v = s[j][r] * 0.125f;
        if (dm && (kv0 + j * 16 + lr > row)) v = -3e38f;
        s[j][r] = v;
        pm = fmaxf(pm, v);
      }
#pragma unroll
      for (int off = 1; off < 16; off <<= 1) pm = fmaxf(pm, __shfl_xor(pm, off));
      float mn = fmaxf(m[r], pm);
      float f = __expf(m[r] - mn);
      m[r] = mn;
      float ps = 0.f;
#pragma unroll
      for (int j = 0; j < 4; ++j){
        float pv = __expf(s[j][r] - mn);
        ps += pv;
        Ps[wid][lk * 4 + r][j * 16 + lr] = f2bf(pv);
      }
#pragma unroll
      for (int off = 1; off < 16; off <<= 1) ps += __shfl_xor(ps, off);
      l[r] = l[r] * f + ps;
#pragma unroll
      for (int j = 0; j < 4; ++j) o[j][r] *= f;
    }
#pragma unroll
    for (int c = 0; c < 2; ++c){
      short8 pa = *(const short8*)&Ps[wid][lr][c * 32 + lk * 8];
#pragma unroll
      for (int j = 0; j < 4; ++j){
        short8 vb = *(const short8*)(Vtb + (long)(j * 16 + lr) * SL + kv0 + c * 32 + lk * 8);
        o[j] = __builtin_amdgcn_mfma_f32_16x16x32_bf16(pa, vb, o[j], 0, 0, 0);
      }
    }
  }
  u16* O = out + (long)(b * SL) * NE + h * HD;
#pragma unroll
  for (int r = 0; r < 4; ++r){
    float inv = 1.f / l[r];
    const int row = qr0 + lk * 4 + r;
#pragma unroll
    for (int j = 0; j < 4; ++j)
      O[(long)row * NE + j * 16 + lr] = f2bf(o[j][r] * inv);
  }
}

// ------- generic bf16 MFMA GEMM, B^T layout, depth-2 counted-vmcnt pipeline -------
// modes: 2 bf16 +bias +gelu(erf), 3 f32 raw, 5 qkv: bf16 +bias, V cols scattered to vt
struct GemmP {
  const u16* A; const u16* B; void* C;
  const float* bias; u16* vt;
  int M, N, K, lda, ldb, ldc, mode;
  long zA, zB, zC;                       // per-blockIdx.z element offsets (split-K)
};

__global__ __launch_bounds__(256) void k_gemm_bt(GemmP p){
  __shared__ u16 As[3][128 * 32];
  __shared__ u16 Bs[3][128 * 32];
  // XCD-aware block swizzle (nwg is always a multiple of 8 here)
  const int nwg = gridDim.x * gridDim.y;
  const int orig = blockIdx.x + blockIdx.y * gridDim.x;
  const int wg = (orig & 7) * (nwg >> 3) + (orig >> 3);
  const int m0 = (wg % gridDim.x) * 128, n0 = (wg / gridDim.x) * 128;
  const u16* A = p.A + (long)blockIdx.z * p.zA;
  const u16* B = p.B + (long)blockIdx.z * p.zB;
  const long offC = (long)blockIdx.z * p.zC;
  const int t = threadIdx.x, lane = t & 63, wid = t >> 6;
  const int wm = (wid >> 1) * 64, wn = (wid & 1) * 64;
  const int lr = lane & 15, lk = lane >> 4;
  const int srow0 = wid * 32 + (lane >> 2);
  const int sseg  = (lane & 3) * 8;
  const u16* Abase = A + (long)(m0 + srow0) * p.lda + sseg;
  const u16* Bbase = B + (long)(n0 + srow0) * p.ldb + sseg;
  auto stage = [&](int buf, int kt){     // 4 gload_lds per thread per K-tile
    const u16* Ab = Abase + kt * 32;
    const u16* Bb = Bbase + kt * 32;
    gload16(Ab,              &As[buf][(wid * 2 + 0) * 512]);
    gload16(Ab + 16 * p.lda, &As[buf][(wid * 2 + 1) * 512]);
    gload16(Bb,              &Bs[buf][(wid * 2 + 0) * 512]);
    gload16(Bb + 16 * p.ldb, &Bs[buf][(wid * 2 + 1) * 512]);
  };
  f32x4 acc[4][4] = {};
  const int nk = p.K >> 5;               // always >= 2 here
  stage(0, 0);
  stage(1, 1);
  int cur = 0;
  for (int kt = 0; kt < nk; ++kt){
    if (kt + 2 < nk){
      int nxt = cur + 2; if (nxt >= 3) nxt -= 3;   // tile kt+2 -> buf (kt+2)%3
      stage(nxt, kt + 2);
    }
    // wait only this tile's 4 loads; leave up to 8 (tiles kt+1, kt+2) in flight
    int rem = nk - 1 - kt;
    waitvm(rem >= 2 ? 8 : rem == 1 ? 4 : 0);
    __builtin_amdgcn_s_barrier();        // all waves' tile-kt loads complete
    short8 af[4], bfr[4];
#pragma unroll
    for (int i = 0; i < 4; ++i) af[i]  = *(const short8*)&As[cur][(wm + i * 16 + lr) * 32 + lk * 8];
#pragma unroll
    for (int j = 0; j < 4; ++j) bfr[j] = *(const short8*)&Bs[cur][(wn + j * 16 + lr) * 32 + lk * 8];
#pragma unroll
    for (int i = 0; i < 4; ++i)
#pragma unroll
      for (int j = 0; j < 4; ++j)
        acc[i][j] = __builtin_amdgcn_mfma_f32_16x16x32_bf16(af[i], bfr[j], acc[i][j], 0, 0, 0);
    asm volatile("s_waitcnt lgkmcnt(0)" ::: "memory");  // ds_reads of buf done
    __builtin_amdgcn_s_barrier();        // before buf is restaged next iter
    cur = (cur == 2) ? 0 : cur + 1;
  }
#pragma unroll
  for (int i = 0; i < 4; ++i){
#pragma unroll
    for (int r = 0; r < 4; ++r){
      int row = m0 + wm + i * 16 + lk * 4 + r;
      if (row >= p.M) continue;
#pragma unroll
      for (int j = 0; j < 4; ++j){
        int col = n0 + wn + j * 16 + lr;
        if (col >= p.N) continue;
        float v = acc[i][j][r];
        long idx = offC + (long)row * p.ldc + col;
        if (p.mode == 5){
          v += p.bias[col];
          if (col >= 2 * NE){
            int d = col - 2 * NE;
            long vidx = (((long)(row >> 10) * NH + (d >> 6)) * HD + (d & 63)) * SL + (row & 1023);
            p.vt[vidx] = f2bf(v);
          } else {
            ((u16*)p.C)[idx] = f2bf(v);
          }
        } else if (p.mode == 2){
          v += p.bias[col];
          v = 0.5f * v * (1.f + erff(v * 0.70710678118f));
          ((u16*)p.C)[idx] = f2bf(v);
        } else {
          ((float*)p.C)[idx] = v;
        }
      }
    }
  }
}

static inline void gemm(hipStream_t s, const u16* A, int lda, const u16* B, int ldb,
    void* C, int ldc, int M, int N, int K, const float* bias, u16* vt, int mode,
    int gz = 1, long zA = 0, long zB = 0, long zC = 0){
  GemmP p{ A, B, C, bias, vt, M, N, K, lda, ldb, ldc, mode, zA, zB, zC };
  dim3 g(M / 128, (N + 127) / 128, gz);
  k_gemm_bt<<<g, 256, 0, s>>>(p);
}

// ======== 256x256 8-wave LM-head GEMM: C[2048][NV] = A[2048][768] * B^T[NVP][768] ========
// T2 XOR-swizzled LDS (linear gload_lds dest + pre-swizzled global src, rule #21),
// T4 counted vmcnt(8) across barriers, T5 setprio around MFMA clusters.
__global__ __launch_bounds__(512, 1) void k_gemm256(const u16* __restrict__ A,
    const u16* __restrict__ B, float* __restrict__ C){
  __shared__ u16 As[2][256 * 64];
  __shared__ u16 Bs[2][256 * 64];
  const int gx = gridDim.x, nwg = gx * gridDim.y;
  const int orig = blockIdx.x + blockIdx.y * gx;
  const int wg = (orig & 7) * (nwg >> 3) + (orig >> 3);   // nwg % 8 == 0
  const int m0 = (wg % gx) * 256, n0 = (wg / gx) * 256;
  const int t = threadIdx.x, lane = t & 63;
  const int lr = lane & 15, lk = lane >> 4;
  const int wid = t >> 6, wr = wid >> 2, wc = wid & 3;    // wave tile 128x64
  // staging: load i covers physical LDS bytes tt*16 (tt = t + i*512):
  // row r = tt>>3, phys slot p = tt&7; fetch logical slot p^(r&7) (swizzle involution)
  const u16* gA[4]; const u16* gB[4]; int ldst[4];
#pragma unroll
  for (int i = 0; i < 4; ++i){
    int tt = t + i * 512, r = tt >> 3, pp = tt & 7, sl = pp ^ (r & 7);
    gA[i] = A + (long)(m0 + r) * NE + sl * 8;
    gB[i] = B + (long)(n0 + r) * NE + sl * 8;
    ldst[i] = tt * 8;                    // u16 offset
  }
  auto stage = [&](int buf, int kt){     // 8 gload16 per thread
#pragma unroll
    for (int i = 0; i < 4; ++i) gload16(gA[i] + kt * 64, &As[buf][ldst[i]]);
#pragma unroll
    for (int i = 0; i < 4; ++i) gload16(gB[i] + kt * 64, &Bs[buf][ldst[i]]);
  };
  // swizzled fragment reads: logical u16 col (kc*32+lk*8) ^ ((row&7)<<3)
  f32x4 acc[8][4] = {};
  const int nk = NE / 64;                // 12 K-tiles
  stage(0, 0);
  for (int kt = 0; kt < nk; ++kt){
    const int buf = kt & 1;
    if (kt + 1 < nk){ stage(buf ^ 1, kt + 1); waitvm(8); }
    else            { waitvm(0); }
    __builtin_amdgcn_sched_barrier(0);
    __builtin_amdgcn_s_barrier();        // tile kt resident in As/Bs[buf]
    __builtin_amdgcn_sched_barrier(0);
    short8 bf[4][2];
#pragma unroll
    for (int nj = 0; nj < 4; ++nj)
#pragma unroll
      for (int kc = 0; kc < 2; ++kc){
        int r = wc * 64 + nj * 16 + lr;
        bf[nj][kc] = *(const short8*)&Bs[buf][r * 64 + ((kc * 32 + lk * 8) ^ ((r & 7) << 3))];
      }
    {
      short8 af[4][2];
#pragma unroll
      for (int mi = 0; mi < 4; ++mi)
#pragma unroll
        for (int kc = 0; kc < 2; ++kc){
          int r = wr * 128 + mi * 16 + lr;
          af[mi][kc] = *(const short8*)&As[buf][r * 64 + ((kc * 32 + lk * 8) ^ ((r & 7) << 3))];
        }
      __builtin_amdgcn_s_setprio(1);
#pragma unroll
      for (int mi = 0; mi < 4; ++mi)
#pragma unroll
        for (int nj = 0; nj < 4; ++nj)
#pragma unroll
          for (int kc = 0; kc < 2; ++kc)
            acc[mi][nj] = __builtin_amdgcn_mfma_f32_16x16x32_bf16(af[mi][kc], bf[nj][kc], acc[mi][nj], 0, 0, 0);
      __builtin_amdgcn_s_setprio(0);
    }
    {
      short8 af[4][2];
#pragma unroll
      for (int mi = 0; mi < 4; ++mi)
#pragma unroll
        for (int kc = 0; kc < 2; ++kc){
          int r = wr * 128 + (mi + 4) * 16 + lr;
          af[mi][kc] = *(const short8*)&As[buf][r * 64 + ((kc * 32 + lk * 8) ^ ((r & 7) << 3))];
        }
      __builtin_amdgcn_s_setprio(1);
#pragma unroll
      for (int mi = 0; mi < 4; ++mi)
#pragma unroll
        for (int nj = 0; nj < 4; ++nj)
#pragma unroll
          for (int kc = 0; kc < 2; ++kc)
            acc[mi + 4][nj] = __builtin_amdgcn_mfma_f32_16x16x32_bf16(af[mi][kc], bf[nj][kc], acc[mi + 4][nj], 0, 0, 0);
      __builtin_amdgcn_s_setprio(0);
    }
    asm volatile("s_waitcnt lgkmcnt(0)" ::: "memory");  // this wave's ds_reads of buf done
    __builtin_amdgcn_sched_barrier(0);
    __builtin_amdgcn_s_barrier();        // all waves done with buf -> restage next iter
  }
#pragma unroll
  for (int mi = 0; mi < 8; ++mi)
#pragma unroll
    for (int r = 0; r < 4; ++r){
      int row = m0 + wr * 128 + mi * 16 + lk * 4 + r;
#pragma unroll
      for (int nj = 0; nj < 4; ++nj){
        int col = n0 + wc * 64 + nj * 16 + lr;
        if (col < NV) C[(long)row * NV + col] = acc[mi][nj][r];
      }
    }
}

extern "C" void kernel_launch(void* const* d_in, const int* in_sizes, int n_in,
                              void* d_out, int out_size, void* d_ws, size_t ws_size,
                              hipStream_t stream){
  (void)in_sizes; (void)n_in; (void)out_size; (void)ws_size;
  const float* x    = (const float*)d_in[0];
  const float* Wqkv = (const float*)d_in[1];
  const float* bqkv = (const float*)d_in[2];
  const float* Wo   = (const float*)d_in[3];
  const float* bo   = (const float*)d_in[4];
  const float* W1   = (const float*)d_in[5];
  const float* b1   = (const float*)d_in[6];
  const float* W2   = (const float*)d_in[7];
  const float* b2   = (const float*)d_in[8];
  const float* ln1g = (const float*)d_in[9];
  const float* ln1b = (const float*)d_in[10];
  const float* ln2g = (const float*)d_in[11];
  const float* ln2b = (const float*)d_in[12];
  const float* lnfg = (const float*)d_in[13];
  const float* lnfb = (const float*)d_in[14];
  const float* Wlm  = (const float*)d_in[15];

  char* ws = (char*)d_ws;
  size_t off = 0;
  auto alloc = [&](size_t bytes){ void* p = ws + off; off += (bytes + 255) & ~255UL; return p; };
  float* h      = (float*)alloc((size_t)TT * NE * 4);
  u16*   a      = (u16*)  alloc((size_t)TT * NE * 2);
  u16*   qkv    = (u16*)  alloc((size_t)TT * QKVD * 2);
  u16*   vtbuf  = (u16*)  alloc((size_t)NB * NH * HD * SL * 2);
  u16*   attno  = (u16*)  alloc((size_t)TT * NE * 2);
  u16*   ffm    = (u16*)  alloc((size_t)TT * DFF * 2);
  float* part   = (float*)alloc((size_t)4 * TT * NE * 4);
  u16*   wqkvT  = (u16*)  alloc((size_t)NL * QKVD * NE * 2);
  u16*   woT    = (u16*)  alloc((size_t)NL * NE * NE * 2);
  u16*   w1T    = (u16*)  alloc((size_t)NL * DFF * NE * 2);
  u16*   w2T    = (u16*)  alloc((size_t)NL * NE * DFF * 2);
  u16*   wlmB   = (u16*)  alloc((size_t)NVP * NE * 2);

  // h = x
  hipMemcpyAsync(h, x, (size_t)TT * NE * 4, hipMemcpyDeviceToDevice, stream);
  // weight conversions
  k_transpose_cvt_all<<<dim3(QKVD / 32, NE / 32, NL), 256, 0, stream>>>(Wqkv, wqkvT, NE, QKVD);
  k_transpose_cvt_all<<<dim3(NE / 32, NE / 32, NL),   256, 0, stream>>>(Wo,   woT,   NE, NE);
  k_transpose_cvt_all<<<dim3(DFF / 32, NE / 32, NL),  256, 0, stream>>>(W1,   w1T,   NE, DFF);
  k_transpose_cvt_all<<<dim3(NE / 32, DFF / 32, NL),  256, 0, stream>>>(W2,   w2T,   DFF, NE);
  k_cvt4<<<2048, 256, 0, stream>>>((const float4*)Wlm, (u16x4*)wlmB, (long)NV * NE / 4);
  hipMemsetAsync(wlmB + (size_t)NV * NE, 0, (size_t)(NVP - NV) * NE * 2, stream);

  // ln1 of layer 0
  k_layernorm<<<TT, 256, 0, stream>>>(h, ln1g, ln1b, a);

  for (int L = 0; L < NL; ++L){
    // qkv = a @ Wqkv + bqkv ; V columns scattered transposed into vtbuf
    gemm(stream, a, NE, wqkvT + (size_t)L * QKVD * NE, NE, qkv, QKVD, TT, QKVD, NE,
         bqkv + (size_t)L * QKVD, vtbuf, 5);
    // fused causal attention -> attno
    k_flash<<<dim3(NB * NH, SL / 64), 256, 0, stream>>>(qkv, vtbuf, attno);
    // proj: split-K x2 partials
    gemm(stream, attno, NE, woT + (size_t)L * NE * NE, NE, part, NE, TT, NE, 384,
         nullptr, nullptr, 3, 2, 384, 384, (long)TT * NE);
    // h += bo + parts; a = ln2(h)
    k_combine_ln<<<TT, 256, 0, stream>>>(h, part, bo + (size_t)L * NE, 2,
         ln2g + (size_t)L * NE, ln2b + (size_t)L * NE, a);
    // ffm = gelu(a @ W1 + b1)
    gemm(stream, a, NE, w1T + (size_t)L * DFF * NE, NE, ffm, DFF, TT, DFF, NE,
         b1 + (size_t)L * DFF, nullptr, 2);
    // ff2: split-K x4 partials
    gemm(stream, ffm, DFF, w2T + (size_t)L * NE * DFF, DFF, part, NE, TT, NE, 768,
         nullptr, nullptr, 3, 4, 768, 768, (long)TT * NE);
    // h += b2 + parts; a = ln1(next) or lnf (last layer)
    const float* gn = (L + 1 < NL) ? ln1g + (size_t)(L + 1) * NE : lnfg;
    const float* bn = (L + 1 < NL) ? ln1b + (size_t)(L + 1) * NE : lnfb;
    k_combine_ln<<<TT, 256, 0, stream>>>(h, part, b2 + (size_t)L * NE, 4, gn, bn, a);
  }
  // logits = a @ Wlm^T  (f32 out) — 256^2 8-wave pipelined GEMM
  k_gemm256<<<dim3(TT / 256, NVP / 256), 512, 0, stream>>>(a, wlmB, (float*)d_out);
}

// Round 9
// 2508.770 us; speedup vs baseline: 1.9897x; 1.1293x over previous
//
#include <hip/hip_runtime.h>
#include <math.h>

typedef unsigned short u16;
typedef u16 u16x8 __attribute__((ext_vector_type(8)));
typedef u16 u16x4 __attribute__((ext_vector_type(4)));
typedef short short8 __attribute__((ext_vector_type(8)));
typedef float f32x4 __attribute__((ext_vector_type(4)));

#define NE 768
#define NH 12
#define NL 12
#define NV 50257
#define NVP 50432   // NV padded to 256 multiple for the 256^2 LM-head GEMM
#define HD 64
#define DFF 3072
#define NB 2
#define SL 1024
#define TT 2048     // NB*SL tokens
#define QKVD 2304   // 3*NE

static __device__ __forceinline__ u16 f2bf(float f){
  unsigned int x; __builtin_memcpy(&x, &f, 4);
  x = (x + 0x7FFFu + ((x >> 16) & 1u)) >> 16;
  return (u16)x;
}

typedef const __attribute__((address_space(1))) unsigned int* gas1_t;
typedef __attribute__((address_space(3))) unsigned int* las3_t;
static __device__ __forceinline__ void gload16(const u16* g, u16* l){
  __builtin_amdgcn_global_load_lds((gas1_t)(const void*)g, (las3_t)(void*)l, 16, 0, 0);
}
// counted vmcnt wait: N loads may remain in flight (wave-uniform arg)
static __device__ __forceinline__ void waitvm(int n){
  switch (n){
    case 0: asm volatile("s_waitcnt vmcnt(0)" ::: "memory"); break;
    case 3: asm volatile("s_waitcnt vmcnt(3)" ::: "memory"); break;
    case 4: asm volatile("s_waitcnt vmcnt(4)" ::: "memory"); break;
    case 6: asm volatile("s_waitcnt vmcnt(6)" ::: "memory"); break;
    default: asm volatile("s_waitcnt vmcnt(8)" ::: "memory"); break;
  }
}

// ---------------- fp32 -> bf16 convert (vectorized) ----------------
__global__ void k_cvt4(const float4* __restrict__ in, u16x4* __restrict__ out, long n4){
  long i = (long)blockIdx.x * blockDim.x + threadIdx.x;
  long st = (long)gridDim.x * blockDim.x;
  for (; i < n4; i += st){
    float4 v = in[i];
    u16x4 o = { f2bf(v.x), f2bf(v.y), f2bf(v.z), f2bf(v.w) };
    out[i] = o;
  }
}

// ------ fp32 [L][K][N] -> bf16 [L][N][K] transpose-convert, all layers ------
__global__ __launch_bounds__(256) void k_transpose_cvt_all(const float* __restrict__ in0,
    u16* __restrict__ out0, int K, int N){
  __shared__ u16 tile[32][33];
  const float* in = in0 + (long)blockIdx.z * K * N;
  u16* out = out0 + (long)blockIdx.z * N * K;
  int n0 = blockIdx.x * 32, k0 = blockIdx.y * 32;
#pragma unroll
  for (int i = 0; i < 4; ++i){
    int e = threadIdx.x + i * 256;
    int r = e >> 5, c = e & 31;          // r: k, c: n
    tile[r][c] = f2bf(in[(long)(k0 + r) * N + (n0 + c)]);
  }
  __syncthreads();
#pragma unroll
  for (int i = 0; i < 4; ++i){
    int e = threadIdx.x + i * 256;
    int r = e >> 5, c = e & 31;          // r: n, c: k
    out[(long)(n0 + r) * K + (k0 + c)] = tile[c][r];
  }
}

// ---------------- LayerNorm: f32 [TT][768] -> bf16 ----------------
__global__ __launch_bounds__(256) void k_layernorm(const float* __restrict__ x,
    const float* __restrict__ g, const float* __restrict__ b, u16* __restrict__ out){
  int row = blockIdx.x;
  const float* xr = x + (long)row * NE;
  int t = threadIdx.x;
  float v[3];
  v[0] = xr[t]; v[1] = xr[t + 256]; v[2] = xr[t + 512];
  float s = v[0] + v[1] + v[2];
  float sq = v[0]*v[0] + v[1]*v[1] + v[2]*v[2];
  __shared__ float red[8];
#pragma unroll
  for (int o = 32; o; o >>= 1){ s += __shfl_xor(s, o); sq += __shfl_xor(sq, o); }
  int wid = t >> 6, lane = t & 63;
  if (!lane){ red[wid] = s; red[4 + wid] = sq; }
  __syncthreads();
  s  = red[0] + red[1] + red[2] + red[3];
  sq = red[4] + red[5] + red[6] + red[7];
  float mean = s * (1.f / NE);
  float var  = sq * (1.f / NE) - mean * mean;
  float rs = rsqrtf(var + 1e-5f);
  u16* orow = out + (long)row * NE;
#pragma unroll
  for (int i = 0; i < 3; ++i){
    int c = t + i * 256;
    orow[c] = f2bf((v[i] - mean) * rs * g[c] + b[c]);
  }
}

// ---- split-K combine + LayerNorm fused: one block per token row ----
__global__ __launch_bounds__(256) void k_combine_ln(float* __restrict__ h,
    const float* __restrict__ part, const float* __restrict__ bias, int nsplit,
    const float* __restrict__ g, const float* __restrict__ b, u16* __restrict__ aout){
  int row = blockIdx.x;
  int t = threadIdx.x;
  float* hr = h + (long)row * NE;
  float v[3];
#pragma unroll
  for (int i = 0; i < 3; ++i){
    int c = t + i * 256;
    float acc = hr[c] + bias[c];
    for (int s = 0; s < nsplit; ++s)
      acc += part[(long)s * TT * NE + (long)row * NE + c];
    v[i] = acc;
    hr[c] = acc;
  }
  float s = v[0] + v[1] + v[2];
  float sq = v[0]*v[0] + v[1]*v[1] + v[2]*v[2];
  __shared__ float red[8];
#pragma unroll
  for (int o = 32; o; o >>= 1){ s += __shfl_xor(s, o); sq += __shfl_xor(sq, o); }
  int wid = t >> 6, lane = t & 63;
  if (!lane){ red[wid] = s; red[4 + wid] = sq; }
  __syncthreads();
  s  = red[0] + red[1] + red[2] + red[3];
  sq = red[4] + red[5] + red[6] + red[7];
  float mean = s * (1.f / NE);
  float var  = sq * (1.f / NE) - mean * mean;
  float rs = rsqrtf(var + 1e-5f);
  u16* orow = aout + (long)row * NE;
#pragma unroll
  for (int i = 0; i < 3; ++i){
    int c = t + i * 256;
    orow[c] = f2bf((v[i] - mean) * rs * g[c] + b[c]);
  }
}

// ---------------- barrier-free fused causal flash attention ----------------
__global__ __launch_bounds__(256) void k_flash(const u16* __restrict__ qkv,
    const u16* __restrict__ vt, u16* __restrict__ out){
  __shared__ u16 Ps[4][16][72];          // wave-private P tile (q x kv)
  const int z = blockIdx.x;
  const int qt = gridDim.y - 1 - blockIdx.y;   // heavy q-tiles dispatch first
  const int b = z / NH, h = z % NH;
  const int q0 = qt * 64;
  const int t = threadIdx.x, lane = t & 63, wid = t >> 6;
  const int lr = lane & 15, lk = lane >> 4;
  const int qr0 = q0 + wid * 16;         // wave's first q row
  const u16* Qp = qkv + (long)(b * SL + qr0 + lr) * QKVD + h * HD;
  short8 aq[2];
  aq[0] = *(const short8*)(Qp + lk * 8);
  aq[1] = *(const short8*)(Qp + 32 + lk * 8);
  const u16* Kb  = qkv + (long)(b * SL) * QKVD + NE + h * HD;
  const u16* Vtb = vt + (long)z * HD * SL;
  f32x4 o[4] = {};
  float m[4], l[4];
#pragma unroll
  for (int r = 0; r < 4; ++r){ m[r] = -3e38f; l[r] = 0.f; }
  const int nt = qt + 1;
  for (int kt = 0; kt < nt; ++kt){
    const int kv0 = kt * 64;
    short8 kb[4][2];
#pragma unroll
    for (int j = 0; j < 4; ++j)
#pragma unroll
      for (int c = 0; c < 2; ++c)
        kb[j][c] = *(const short8*)(Kb + (long)(kv0 + j * 16 + lr) * QKVD + c * 32 + lk * 8);
    f32x4 s[4] = {};
#pragma unroll
    for (int c = 0; c < 2; ++c)
#pragma unroll
      for (int j = 0; j < 4; ++j)
        s[j] = __builtin_amdgcn_mfma_f32_16x16x32_bf16(aq[c], kb[j][c], s[j], 0, 0, 0);
    const bool dm = (kt == nt - 1);
#pragma unroll
    for (int r = 0; r < 4; ++r){
      const int row = qr0 + lk * 4 + r;
      float pm = -3e38f;
#pragma unroll
      for (int j = 0; j < 4; ++j){
        float v = s[j][r] * 0.125f;
        if (dm && (kv0 + j * 16 + lr > row)) v = -3e38f;
        s[j][r] = v;
        pm = fmaxf(pm, v);
      }
#pragma unroll
      for (int off = 1; off < 16; off <<= 1) pm = fmaxf(pm, __shfl_xor(pm, off));
      float mn = fmaxf(m[r], pm);
      float f = __expf(m[r] - mn);
      m[r] = mn;
      float ps = 0.f;
#pragma unroll
      for (int j = 0; j < 4; ++j){
        float pv = __expf(s[j][r] - mn);
        ps += pv;
        Ps[wid][lk * 4 + r][j * 16 + lr] = f2bf(pv);
      }
#pragma unroll
      for (int off = 1; off < 16; off <<= 1) ps += __shfl_xor(ps, off);
      l[r] = l[r] * f + ps;
#pragma unroll
      for (int j = 0; j < 4; ++j) o[j][r] *= f;
    }
#pragma unroll
    for (int c = 0; c < 2; ++c){
      short8 pa = *(const short8*)&Ps[wid][lr][c * 32 + lk * 8];
#pragma unroll
      for (int j = 0; j < 4; ++j){
        short8 vb = *(const short8*)(Vtb + (long)(j * 16 + lr) * SL + kv0 + c * 32 + lk * 8);
        o[j] = __builtin_amdgcn_mfma_f32_16x16x32_bf16(pa, vb, o[j], 0, 0, 0);
      }
    }
  }
  u16* O = out + (long)(b * SL) * NE + h * HD;
#pragma unroll
  for (int r = 0; r < 4; ++r){
    float inv = 1.f / l[r];
    const int row = qr0 + lk * 4 + r;
#pragma unroll
    for (int j = 0; j < 4; ++j)
      O[(long)row * NE + j * 16 + lr] = f2bf(o[j][r] * inv);
  }
}

// --- generic bf16 MFMA GEMM, 64x128 tile, B^T layout, 3-buf counted-vmcnt ring ---
// modes: 2 bf16 +bias +gelu(erf), 3 f32 raw, 5 qkv: bf16 +bias, V cols scattered to vt
struct GemmP {
  const u16* A; const u16* B; void* C;
  const float* bias; u16* vt;
  int M, N, K, lda, ldb, ldc, mode;
  long zA, zB, zC;                       // per-blockIdx.z element offsets (split-K)
};

__global__ __launch_bounds__(256) void k_gemm_bt(GemmP p){
  __shared__ u16 As[3][64 * 32];
  __shared__ u16 Bs[3][128 * 32];
  // XCD-aware block swizzle (nwg is always a multiple of 8 here)
  const int nwg = gridDim.x * gridDim.y;
  const int orig = blockIdx.x + blockIdx.y * gridDim.x;
  const int wg = (orig & 7) * (nwg >> 3) + (orig >> 3);
  const int m0 = (wg % gridDim.x) * 64, n0 = (wg / gridDim.x) * 128;
  const u16* A = p.A + (long)blockIdx.z * p.zA;
  const u16* B = p.B + (long)blockIdx.z * p.zB;
  const long offC = (long)blockIdx.z * p.zC;
  const int t = threadIdx.x, lane = t & 63, wid = t >> 6;
  const int wm = (wid >> 1) * 32, wn = (wid & 1) * 64;
  const int lr = lane & 15, lk = lane >> 4;
  const int srow = t >> 2;               // [0,64)
  const int sseg = (t & 3) * 8;
  const u16* Abase  = A + (long)(m0 + srow) * p.lda + sseg;
  const u16* Bbase  = B + (long)(n0 + srow) * p.ldb + sseg;
  const u16* Bbase2 = B + (long)(n0 + 64 + srow) * p.ldb + sseg;
  auto stage = [&](int buf, int kt){     // 3 gload_lds per thread per K-tile
    gload16(Abase  + kt * 32, &As[buf][t * 8]);
    gload16(Bbase  + kt * 32, &Bs[buf][t * 8]);
    gload16(Bbase2 + kt * 32, &Bs[buf][(t + 256) * 8]);
  };
  f32x4 acc[2][4] = {};
  const int nk = p.K >> 5;               // always >= 2 here
  stage(0, 0);
  stage(1, 1);
  int cur = 0;
  for (int kt = 0; kt < nk; ++kt){
    if (kt + 2 < nk){
      int nxt = cur + 2; if (nxt >= 3) nxt -= 3;   // tile kt+2 -> buf (kt+2)%3
      stage(nxt, kt + 2);
    }
    // wait only this tile's 3 loads; leave up to 6 (tiles kt+1, kt+2) in flight
    int rem = nk - 1 - kt;
    waitvm(rem >= 2 ? 6 : rem == 1 ? 3 : 0);
    __builtin_amdgcn_s_barrier();        // all waves' tile-kt loads complete
    short8 af[2], bfr[4];
#pragma unroll
    for (int i = 0; i < 2; ++i) af[i]  = *(const short8*)&As[cur][(wm + i * 16 + lr) * 32 + lk * 8];
#pragma unroll
    for (int j = 0; j < 4; ++j) bfr[j] = *(const short8*)&Bs[cur][(wn + j * 16 + lr) * 32 + lk * 8];
#pragma unroll
    for (int i = 0; i < 2; ++i)
#pragma unroll
      for (int j = 0; j < 4; ++j)
        acc[i][j] = __builtin_amdgcn_mfma_f32_16x16x32_bf16(af[i], bfr[j], acc[i][j], 0, 0, 0);
    asm volatile("s_waitcnt lgkmcnt(0)" ::: "memory");  // ds_reads of buf done
    __builtin_amdgcn_s_barrier();        // before buf is restaged next iter
    cur = (cur == 2) ? 0 : cur + 1;
  }
#pragma unroll
  for (int i = 0; i < 2; ++i){
#pragma unroll
    for (int r = 0; r < 4; ++r){
      int row = m0 + wm + i * 16 + lk * 4 + r;
      if (row >= p.M) continue;
#pragma unroll
      for (int j = 0; j < 4; ++j){
        int col = n0 + wn + j * 16 + lr;
        if (col >= p.N) continue;
        float v = acc[i][j][r];
        long idx = offC + (long)row * p.ldc + col;
        if (p.mode == 5){
          v += p.bias[col];
          if (col >= 2 * NE){
            int d = col - 2 * NE;
            long vidx = (((long)(row >> 10) * NH + (d >> 6)) * HD + (d & 63)) * SL + (row & 1023);
            p.vt[vidx] = f2bf(v);
          } else {
            ((u16*)p.C)[idx] = f2bf(v);
          }
        } else if (p.mode == 2){
          v += p.bias[col];
          v = 0.5f * v * (1.f + erff(v * 0.70710678118f));
          ((u16*)p.C)[idx] = f2bf(v);
        } else {
          ((float*)p.C)[idx] = v;
        }
      }
    }
  }
}

static inline void gemm(hipStream_t s, const u16* A, int lda, const u16* B, int ldb,
    void* C, int ldc, int M, int N, int K, const float* bias, u16* vt, int mode,
    int gz = 1, long zA = 0, long zB = 0, long zC = 0){
  GemmP p{ A, B, C, bias, vt, M, N, K, lda, ldb, ldc, mode, zA, zB, zC };
  dim3 g(M / 64, (N + 127) / 128, gz);
  k_gemm_bt<<<g, 256, 0, s>>>(p);
}

// ======== 256x256 16-wave LM-head GEMM: C[2048][NV] = A[2048][768] * B^T[NVP][768] ========
// T2 XOR-swizzled LDS (linear gload_lds dest + pre-swizzled global src, rule #21),
// T4 counted vmcnt(4) across barriers, T5 setprio, 4 waves/SIMD for latency hiding.
__global__ __launch_bounds__(1024, 4) void k_gemm256(const u16* __restrict__ A,
    const u16* __restrict__ B, float* __restrict__ C){
  __shared__ u16 As[2][256 * 64];
  __shared__ u16 Bs[2][256 * 64];
  const int gx = gridDim.x, nwg = gx * gridDim.y;
  const int orig = blockIdx.x + blockIdx.y * gx;
  const int wg = (orig & 7) * (nwg >> 3) + (orig >> 3);   // nwg % 8 == 0
  const int m0 = (wg % gx) * 256, n0 = (wg / gx) * 256;
  const int t = threadIdx.x, lane = t & 63;
  const int lr = lane & 15, lk = lane >> 4;
  const int wid = t >> 6, wr = wid >> 2, wc = wid & 3;    // wave tile 64x64
  // staging: load i covers physical LDS bytes tt*16 (tt = t + i*1024):
  // row r = tt>>3, phys slot p = tt&7; fetch logical slot p^(r&7) (swizzle involution)
  const u16* gA[2]; const u16* gB[2]; int ldst[2];
#pragma unroll
  for (int i = 0; i < 2; ++i){
    int tt = t + i * 1024, r = tt >> 3, pp = tt & 7, sl = pp ^ (r & 7);
    gA[i] = A + (long)(m0 + r) * NE + sl * 8;
    gB[i] = B + (long)(n0 + r) * NE + sl * 8;
    ldst[i] = tt * 8;                    // u16 offset
  }
  auto stage = [&](int buf, int kt){     // 4 gload16 per thread
#pragma unroll
    for (int i = 0; i < 2; ++i) gload16(gA[i] + kt * 64, &As[buf][ldst[i]]);
#pragma unroll
    for (int i = 0; i < 2; ++i) gload16(gB[i] + kt * 64, &Bs[buf][ldst[i]]);
  };
  // swizzled fragment reads: logical u16 col (kc*32+lk*8) ^ ((row&7)<<3)
  f32x4 acc[4][4] = {};
  const int nk = NE / 64;                // 12 K-tiles
  stage(0, 0);
  for (int kt = 0; kt < nk; ++kt){
    const int buf = kt & 1;
    if (kt + 1 < nk){ stage(buf ^ 1, kt + 1); waitvm(4); }
    else            { waitvm(0); }
    __builtin_amdgcn_sched_barrier(0);
    __builtin_amdgcn_s_barrier();        // tile kt resident in As/Bs[buf]
    __builtin_amdgcn_sched_barrier(0);
    short8 bf[4][2];
#pragma unroll
    for (int nj = 0; nj < 4; ++nj)
#pragma unroll
      for (int kc = 0; kc < 2; ++kc){
        int r = wc * 64 + nj * 16 + lr;
        bf[nj][kc] = *(const short8*)&Bs[buf][r * 64 + ((kc * 32 + lk * 8) ^ ((r & 7) << 3))];
      }
#pragma unroll
    for (int mh = 0; mh < 2; ++mh){      // two clusters of 16 MFMA (reg pressure)
      short8 af[2][2];
#pragma unroll
      for (int mi = 0; mi < 2; ++mi)
#pragma unroll
        for (int kc = 0; kc < 2; ++kc){
          int r = wr * 64 + (mh * 2 + mi) * 16 + lr;
          af[mi][kc] = *(const short8*)&As[buf][r * 64 + ((kc * 32 + lk * 8) ^ ((r & 7) << 3))];
        }
      __builtin_amdgcn_s_setprio(1);
#pragma unroll
      for (int mi = 0; mi < 2; ++mi)
#pragma unroll
        for (int nj = 0; nj < 4; ++nj)
#pragma unroll
          for (int kc = 0; kc < 2; ++kc)
            acc[mh * 2 + mi][nj] = __builtin_amdgcn_mfma_f32_16x16x32_bf16(af[mi][kc], bf[nj][kc], acc[mh * 2 + mi][nj], 0, 0, 0);
      __builtin_amdgcn_s_setprio(0);
    }
    asm volatile("s_waitcnt lgkmcnt(0)" ::: "memory");  // this wave's ds_reads of buf done
    __builtin_amdgcn_sched_barrier(0);
    __builtin_amdgcn_s_barrier();        // all waves done with buf -> restage next iter
  }
#pragma unroll
  for (int mi = 0; mi < 4; ++mi)
#pragma unroll
    for (int r = 0; r < 4; ++r){
      int row = m0 + wr * 64 + mi * 16 + lk * 4 + r;
#pragma unroll
      for (int nj = 0; nj < 4; ++nj){
        int col = n0 + wc * 64 + nj * 16 + lr;
        if (col < NV) C[(long)row * NV + col] = acc[mi][nj][r];
      }
    }
}

extern "C" void kernel_launch(void* const* d_in, const int* in_sizes, int n_in,
                              void* d_out, int out_size, void* d_ws, size_t ws_size,
                              hipStream_t stream){
  (void)in_sizes; (void)n_in; (void)out_size; (void)ws_size;
  const float* x    = (const float*)d_in[0];
  const float* Wqkv = (const float*)d_in[1];
  const float* bqkv = (const float*)d_in[2];
  const float* Wo   = (const float*)d_in[3];
  const float* bo   = (const float*)d_in[4];
  const float* W1   = (const float*)d_in[5];
  const float* b1   = (const float*)d_in[6];
  const float* W2   = (const float*)d_in[7];
  const float* b2   = (const float*)d_in[8];
  const float* ln1g = (const float*)d_in[9];
  const float* ln1b = (const float*)d_in[10];
  const float* ln2g = (const float*)d_in[11];
  const float* ln2b = (const float*)d_in[12];
  const float* lnfg = (const float*)d_in[13];
  const float* lnfb = (const float*)d_in[14];
  const float* Wlm  = (const float*)d_in[15];

  char* ws = (char*)d_ws;
  size_t off = 0;
  auto alloc = [&](size_t bytes){ void* p = ws + off; off += (bytes + 255) & ~255UL; return p; };
  float* h      = (float*)alloc((size_t)TT * NE * 4);
  u16*   a      = (u16*)  alloc((size_t)TT * NE * 2);
  u16*   qkv    = (u16*)  alloc((size_t)TT * QKVD * 2);
  u16*   vtbuf  = (u16*)  alloc((size_t)NB * NH * HD * SL * 2);
  u16*   attno  = (u16*)  alloc((size_t)TT * NE * 2);
  u16*   ffm    = (u16*)  alloc((size_t)TT * DFF * 2);
  float* part   = (float*)alloc((size_t)4 * TT * NE * 4);
  u16*   wqkvT  = (u16*)  alloc((size_t)NL * QKVD * NE * 2);
  u16*   woT    = (u16*)  alloc((size_t)NL * NE * NE * 2);
  u16*   w1T    = (u16*)  alloc((size_t)NL * DFF * NE * 2);
  u16*   w2T    = (u16*)  alloc((size_t)NL * NE * DFF * 2);
  u16*   wlmB   = (u16*)  alloc((size_t)NVP * NE * 2);

  // h = x
  hipMemcpyAsync(h, x, (size_t)TT * NE * 4, hipMemcpyDeviceToDevice, stream);
  // weight conversions
  k_transpose_cvt_all<<<dim3(QKVD / 32, NE / 32, NL), 256, 0, stream>>>(Wqkv, wqkvT, NE, QKVD);
  k_transpose_cvt_all<<<dim3(NE / 32, NE / 32, NL),   256, 0, stream>>>(Wo,   woT,   NE, NE);
  k_transpose_cvt_all<<<dim3(DFF / 32, NE / 32, NL),  256, 0, stream>>>(W1,   w1T,   NE, DFF);
  k_transpose_cvt_all<<<dim3(NE / 32, DFF / 32, NL),  256, 0, stream>>>(W2,   w2T,   DFF, NE);
  k_cvt4<<<2048, 256, 0, stream>>>((const float4*)Wlm, (u16x4*)wlmB, (long)NV * NE / 4);
  hipMemsetAsync(wlmB + (size_t)NV * NE, 0, (size_t)(NVP - NV) * NE * 2, stream);

  // ln1 of layer 0
  k_layernorm<<<TT, 256, 0, stream>>>(h, ln1g, ln1b, a);

  for (int L = 0; L < NL; ++L){
    // qkv = a @ Wqkv + bqkv ; V columns scattered transposed into vtbuf
    gemm(stream, a, NE, wqkvT + (size_t)L * QKVD * NE, NE, qkv, QKVD, TT, QKVD, NE,
         bqkv + (size_t)L * QKVD, vtbuf, 5);
    // fused causal attention -> attno
    k_flash<<<dim3(NB * NH, SL / 64), 256, 0, stream>>>(qkv, vtbuf, attno);
    // proj: split-K x2 partials
    gemm(stream, attno, NE, woT + (size_t)L * NE * NE, NE, part, NE, TT, NE, 384,
         nullptr, nullptr, 3, 2, 384, 384, (long)TT * NE);
    // h += bo + parts; a = ln2(h)
    k_combine_ln<<<TT, 256, 0, stream>>>(h, part, bo + (size_t)L * NE, 2,
         ln2g + (size_t)L * NE, ln2b + (size_t)L * NE, a);
    // ffm = gelu(a @ W1 + b1)
    gemm(stream, a, NE, w1T + (size_t)L * DFF * NE, NE, ffm, DFF, TT, DFF, NE,
         b1 + (size_t)L * DFF, nullptr, 2);
    // ff2: split-K x4 partials
    gemm(stream, ffm, DFF, w2T + (size_t)L * NE * DFF, DFF, part, NE, TT, NE, 768,
         nullptr, nullptr, 3, 4, 768, 768, (long)TT * NE);
    // h += b2 + parts; a = ln1(next) or lnf (last layer)
    const float* gn = (L + 1 < NL) ? ln1g + (size_t)(L + 1) * NE : lnfg;
    const float* bn = (L + 1 < NL) ? ln1b + (size_t)(L + 1) * NE : lnfb;
    k_combine_ln<<<TT, 256, 0, stream>>>(h, part, b2 + (size_t)L * NE, 4, gn, bn, a);
  }
  // logits = a @ Wlm^T  (f32 out) — 256^2 16-wave pipelined GEMM
  k_gemm256<<<dim3(TT / 256, NVP / 256), 1024, 0, stream>>>(a, wlmB, (float*)d_out);
}

// Round 10
// 2473.826 us; speedup vs baseline: 2.0178x; 1.0141x over previous
//
#include <hip/hip_runtime.h>
#include <math.h>

typedef unsigned short u16;
typedef u16 u16x8 __attribute__((ext_vector_type(8)));
typedef u16 u16x4 __attribute__((ext_vector_type(4)));
typedef short short8 __attribute__((ext_vector_type(8)));
typedef float f32x4 __attribute__((ext_vector_type(4)));

#define NE 768
#define NH 12
#define NL 12
#define NV 50257
#define NVP 50432   // NV padded to 256 multiple for the 256^2 LM-head GEMM
#define HD 64
#define DFF 3072
#define NB 2
#define SL 1024
#define TT 2048     // NB*SL tokens
#define QKVD 2304   // 3*NE

static __device__ __forceinline__ u16 f2bf(float f){
  unsigned int x; __builtin_memcpy(&x, &f, 4);
  x = (x + 0x7FFFu + ((x >> 16) & 1u)) >> 16;
  return (u16)x;
}

typedef const __attribute__((address_space(1))) unsigned int* gas1_t;
typedef __attribute__((address_space(3))) unsigned int* las3_t;
static __device__ __forceinline__ void gload16(const u16* g, u16* l){
  __builtin_amdgcn_global_load_lds((gas1_t)(const void*)g, (las3_t)(void*)l, 16, 0, 0);
}
// counted vmcnt wait: N loads may remain in flight (wave-uniform arg)
static __device__ __forceinline__ void waitvm(int n){
  switch (n){
    case 0: asm volatile("s_waitcnt vmcnt(0)" ::: "memory"); break;
    case 3: asm volatile("s_waitcnt vmcnt(3)" ::: "memory"); break;
    case 4: asm volatile("s_waitcnt vmcnt(4)" ::: "memory"); break;
    case 6: asm volatile("s_waitcnt vmcnt(6)" ::: "memory"); break;
    default: asm volatile("s_waitcnt vmcnt(8)" ::: "memory"); break;
  }
}

// ---------------- fp32 -> bf16 convert (vectorized) ----------------
__global__ void k_cvt4(const float4* __restrict__ in, u16x4* __restrict__ out, long n4){
  long i = (long)blockIdx.x * blockDim.x + threadIdx.x;
  long st = (long)gridDim.x * blockDim.x;
  for (; i < n4; i += st){
    float4 v = in[i];
    u16x4 o = { f2bf(v.x), f2bf(v.y), f2bf(v.z), f2bf(v.w) };
    out[i] = o;
  }
}

// ------ fp32 [L][K][N] -> bf16 [L][N][K] transpose-convert, all layers ------
__global__ __launch_bounds__(256) void k_transpose_cvt_all(const float* __restrict__ in0,
    u16* __restrict__ out0, int K, int N){
  __shared__ u16 tile[32][33];
  const float* in = in0 + (long)blockIdx.z * K * N;
  u16* out = out0 + (long)blockIdx.z * N * K;
  int n0 = blockIdx.x * 32, k0 = blockIdx.y * 32;
#pragma unroll
  for (int i = 0; i < 4; ++i){
    int e = threadIdx.x + i * 256;
    int r = e >> 5, c = e & 31;          // r: k, c: n
    tile[r][c] = f2bf(in[(long)(k0 + r) * N + (n0 + c)]);
  }
  __syncthreads();
#pragma unroll
  for (int i = 0; i < 4; ++i){
    int e = threadIdx.x + i * 256;
    int r = e >> 5, c = e & 31;          // r: n, c: k
    out[(long)(n0 + r) * K + (k0 + c)] = tile[c][r];
  }
}

// ---------------- LayerNorm: f32 [TT][768] -> bf16 ----------------
__global__ __launch_bounds__(256) void k_layernorm(const float* __restrict__ x,
    const float* __restrict__ g, const float* __restrict__ b, u16* __restrict__ out){
  int row = blockIdx.x;
  const float* xr = x + (long)row * NE;
  int t = threadIdx.x;
  float v[3];
  v[0] = xr[t]; v[1] = xr[t + 256]; v[2] = xr[t + 512];
  float s = v[0] + v[1] + v[2];
  float sq = v[0]*v[0] + v[1]*v[1] + v[2]*v[2];
  __shared__ float red[8];
#pragma unroll
  for (int o = 32; o; o >>= 1){ s += __shfl_xor(s, o); sq += __shfl_xor(sq, o); }
  int wid = t >> 6, lane = t & 63;
  if (!lane){ red[wid] = s; red[4 + wid] = sq; }
  __syncthreads();
  s  = red[0] + red[1] + red[2] + red[3];
  sq = red[4] + red[5] + red[6] + red[7];
  float mean = s * (1.f / NE);
  float var  = sq * (1.f / NE) - mean * mean;
  float rs = rsqrtf(var + 1e-5f);
  u16* orow = out + (long)row * NE;
#pragma unroll
  for (int i = 0; i < 3; ++i){
    int c = t + i * 256;
    orow[c] = f2bf((v[i] - mean) * rs * g[c] + b[c]);
  }
}

// ---- split-K combine + LayerNorm fused: one block per token row ----
__global__ __launch_bounds__(256) void k_combine_ln(float* __restrict__ h,
    const float* __restrict__ part, const float* __restrict__ bias, int nsplit,
    const float* __restrict__ g, const float* __restrict__ b, u16* __restrict__ aout){
  int row = blockIdx.x;
  int t = threadIdx.x;
  float* hr = h + (long)row * NE;
  float v[3];
#pragma unroll
  for (int i = 0; i < 3; ++i){
    int c = t + i * 256;
    float acc = hr[c] + bias[c];
    for (int s = 0; s < nsplit; ++s)
      acc += part[(long)s * TT * NE + (long)row * NE + c];
    v[i] = acc;
    hr[c] = acc;
  }
  float s = v[0] + v[1] + v[2];
  float sq = v[0]*v[0] + v[1]*v[1] + v[2]*v[2];
  __shared__ float red[8];
#pragma unroll
  for (int o = 32; o; o >>= 1){ s += __shfl_xor(s, o); sq += __shfl_xor(sq, o); }
  int wid = t >> 6, lane = t & 63;
  if (!lane){ red[wid] = s; red[4 + wid] = sq; }
  __syncthreads();
  s  = red[0] + red[1] + red[2] + red[3];
  sq = red[4] + red[5] + red[6] + red[7];
  float mean = s * (1.f / NE);
  float var  = sq * (1.f / NE) - mean * mean;
  float rs = rsqrtf(var + 1e-5f);
  u16* orow = aout + (long)row * NE;
#pragma unroll
  for (int i = 0; i < 3; ++i){
    int c = t + i * 256;
    orow[c] = f2bf((v[i] - mean) * rs * g[c] + b[c]);
  }
}

// ---------------- barrier-free fused causal flash attention ----------------
// 2-wave blocks, 32 q-rows per block, grid (24 bh, 32 q-tiles) heavy-first.
__global__ __launch_bounds__(128) void k_flash(const u16* __restrict__ qkv,
    const u16* __restrict__ vt, u16* __restrict__ out){
  __shared__ u16 Ps[2][16][72];          // wave-private P tile (q x kv)
  const int z = blockIdx.x;
  const int qt = gridDim.y - 1 - blockIdx.y;   // heavy q-tiles dispatch first
  const int b = z / NH, h = z % NH;
  const int t = threadIdx.x, lane = t & 63, wid = t >> 6;
  const int lr = lane & 15, lk = lane >> 4;
  const int qr0 = qt * 32 + wid * 16;    // wave's first q row
  const u16* Qp = qkv + (long)(b * SL + qr0 + lr) * QKVD + h * HD;
  short8 aq[2];
  aq[0] = *(const short8*)(Qp + lk * 8);
  aq[1] = *(const short8*)(Qp + 32 + lk * 8);
  const u16* Kb  = qkv + (long)(b * SL) * QKVD + NE + h * HD;
  const u16* Vtb = vt + (long)z * HD * SL;
  f32x4 o[4] = {};
  float m[4], l[4];
#pragma unroll
  for (int r = 0; r < 4; ++r){ m[r] = -3e38f; l[r] = 0.f; }
  const int nt = (qt * 32 + 31) / 64 + 1;
  for (int kt = 0; kt < nt; ++kt){
    const int kv0 = kt * 64;
    short8 kb[4][2];
#pragma unroll
    for (int j = 0; j < 4; ++j)
#pragma unroll
      for (int c = 0; c < 2; ++c)
        kb[j][c] = *(const short8*)(Kb + (long)(kv0 + j * 16 + lr) * QKVD + c * 32 + lk * 8);
    f32x4 s[4] = {};
#pragma unroll
    for (int c = 0; c < 2; ++c)
#pragma unroll
      for (int j = 0; j < 4; ++j)
        s[j] = __builtin_amdgcn_mfma_f32_16x16x32_bf16(aq[c], kb[j][c], s[j], 0, 0, 0);
    const bool dm = (kt == nt - 1);
#pragma unroll
    for (int r = 0; r < 4; ++r){
      const int row = qr0 + lk * 4 + r;
      float pm = -3e38f;
#pragma unroll
      for (int j = 0; j < 4; ++j){
        float v = s[j][r] * 0.125f;
        if (dm && (kv0 + j * 16 + lr > row)) v = -3e38f;
        s[j][r] = v;
        pm = fmaxf(pm, v);
      }
#pragma unroll
      for (int off = 1; off < 16; off <<= 1) pm = fmaxf(pm, __shfl_xor(pm, off));
      float mn = fmaxf(m[r], pm);
      float f = __expf(m[r] - mn);
      m[r] = mn;
      float ps = 0.f;
#pragma unroll
      for (int j = 0; j < 4; ++j){
        float pv = __expf(s[j][r] - mn);
        ps += pv;
        Ps[wid][lk * 4 + r][j * 16 + lr] = f2bf(pv);
      }
#pragma unroll
      for (int off = 1; off < 16; off <<= 1) ps += __shfl_xor(ps, off);
      l[r] = l[r] * f + ps;
#pragma unroll
      for (int j = 0; j < 4; ++j) o[j][r] *= f;
    }
#pragma unroll
    for (int c = 0; c < 2; ++c){
      short8 pa = *(const short8*)&Ps[wid][lr][c * 32 + lk * 8];
#pragma unroll
      for (int j = 0; j < 4; ++j){
        short8 vb = *(const short8*)(Vtb + (long)(j * 16 + lr) * SL + kv0 + c * 32 + lk * 8);
        o[j] = __builtin_amdgcn_mfma_f32_16x16x32_bf16(pa, vb, o[j], 0, 0, 0);
      }
    }
  }
  u16* O = out + (long)(b * SL) * NE + h * HD;
#pragma unroll
  for (int r = 0; r < 4; ++r){
    float inv = 1.f / l[r];
    const int row = qr0 + lk * 4 + r;
#pragma unroll
    for (int j = 0; j < 4; ++j)
      O[(long)row * NE + j * 16 + lr] = f2bf(o[j][r] * inv);
  }
}

// --- generic bf16 MFMA GEMM, 64x128 tile, B^T layout, 3-buf counted-vmcnt ring ---
// modes: 2 bf16 +bias +gelu(erf), 3 f32 raw, 5 qkv: bf16 +bias, V cols scattered to vt
struct GemmP {
  const u16* A; const u16* B; void* C;
  const float* bias; u16* vt;
  int M, N, K, lda, ldb, ldc, mode;
  long zA, zB, zC;                       // per-blockIdx.z element offsets (split-K)
};

__global__ __launch_bounds__(256) void k_gemm_bt(GemmP p){
  __shared__ u16 As[3][64 * 32];
  __shared__ u16 Bs[3][128 * 32];
  // XCD-aware block swizzle (nwg is always a multiple of 8 here)
  const int nwg = gridDim.x * gridDim.y;
  const int orig = blockIdx.x + blockIdx.y * gridDim.x;
  const int wg = (orig & 7) * (nwg >> 3) + (orig >> 3);
  const int m0 = (wg % gridDim.x) * 64, n0 = (wg / gridDim.x) * 128;
  const u16* A = p.A + (long)blockIdx.z * p.zA;
  const u16* B = p.B + (long)blockIdx.z * p.zB;
  const long offC = (long)blockIdx.z * p.zC;
  const int t = threadIdx.x, lane = t & 63, wid = t >> 6;
  const int wm = (wid >> 1) * 32, wn = (wid & 1) * 64;
  const int lr = lane & 15, lk = lane >> 4;
  const int srow = t >> 2;               // [0,64)
  const int sseg = (t & 3) * 8;
  const u16* Abase  = A + (long)(m0 + srow) * p.lda + sseg;
  const u16* Bbase  = B + (long)(n0 + srow) * p.ldb + sseg;
  const u16* Bbase2 = B + (long)(n0 + 64 + srow) * p.ldb + sseg;
  auto stage = [&](int buf, int kt){     // 3 gload_lds per thread per K-tile
    gload16(Abase  + kt * 32, &As[buf][t * 8]);
    gload16(Bbase  + kt * 32, &Bs[buf][t * 8]);
    gload16(Bbase2 + kt * 32, &Bs[buf][(t + 256) * 8]);
  };
  f32x4 acc[2][4] = {};
  const int nk = p.K >> 5;               // always >= 2 here
  stage(0, 0);
  stage(1, 1);
  int cur = 0;
  for (int kt = 0; kt < nk; ++kt){
    if (kt + 2 < nk){
      int nxt = cur + 2; if (nxt >= 3) nxt -= 3;   // tile kt+2 -> buf (kt+2)%3
      stage(nxt, kt + 2);
    }
    // wait only this tile's 3 loads; leave up to 6 (tiles kt+1, kt+2) in flight
    int rem = nk - 1 - kt;
    waitvm(rem >= 2 ? 6 : rem == 1 ? 3 : 0);
    __builtin_amdgcn_s_barrier();        // all waves' tile-kt loads complete
    short8 af[2], bfr[4];
#pragma unroll
    for (int i = 0; i < 2; ++i) af[i]  = *(const short8*)&As[cur][(wm + i * 16 + lr) * 32 + lk * 8];
#pragma unroll
    for (int j = 0; j < 4; ++j) bfr[j] = *(const short8*)&Bs[cur][(wn + j * 16 + lr) * 32 + lk * 8];
#pragma unroll
    for (int i = 0; i < 2; ++i)
#pragma unroll
      for (int j = 0; j < 4; ++j)
        acc[i][j] = __builtin_amdgcn_mfma_f32_16x16x32_bf16(af[i], bfr[j], acc[i][j], 0, 0, 0);
    asm volatile("s_waitcnt lgkmcnt(0)" ::: "memory");  // ds_reads of buf done
    __builtin_amdgcn_s_barrier();        // before buf is restaged next iter
    cur = (cur == 2) ? 0 : cur + 1;
  }
#pragma unroll
  for (int i = 0; i < 2; ++i){
#pragma unroll
    for (int r = 0; r < 4; ++r){
      int row = m0 + wm + i * 16 + lk * 4 + r;
      if (row >= p.M) continue;
#pragma unroll
      for (int j = 0; j < 4; ++j){
        int col = n0 + wn + j * 16 + lr;
        if (col >= p.N) continue;
        float v = acc[i][j][r];
        long idx = offC + (long)row * p.ldc + col;
        if (p.mode == 5){
          v += p.bias[col];
          if (col >= 2 * NE){
            int d = col - 2 * NE;
            long vidx = (((long)(row >> 10) * NH + (d >> 6)) * HD + (d & 63)) * SL + (row & 1023);
            p.vt[vidx] = f2bf(v);
          } else {
            ((u16*)p.C)[idx] = f2bf(v);
          }
        } else if (p.mode == 2){
          v += p.bias[col];
          v = 0.5f * v * (1.f + erff(v * 0.70710678118f));
          ((u16*)p.C)[idx] = f2bf(v);
        } else {
          ((float*)p.C)[idx] = v;
        }
      }
    }
  }
}

static inline void gemm(hipStream_t s, const u16* A, int lda, const u16* B, int ldb,
    void* C, int ldc, int M, int N, int K, const float* bias, u16* vt, int mode,
    int gz = 1, long zA = 0, long zB = 0, long zC = 0){
  GemmP p{ A, B, C, bias, vt, M, N, K, lda, ldb, ldc, mode, zA, zB, zC };
  dim3 g(M / 64, (N + 127) / 128, gz);
  k_gemm_bt<<<g, 256, 0, s>>>(p);
}

// ======== 256x256 8-wave LM-head GEMM, BK=32, 3-buffer counted-vmcnt ring ========
// Per-wave 128x64 (LDS-balanced 0.375 reads/MFMA). 4-slot swizzle (slot^=r&3) on
// 64B LDS rows (4-way conflict, accepted). T4 vmcnt(8/4/0), T5 setprio clusters.
__global__ __launch_bounds__(512, 1) void k_gemm256(const u16* __restrict__ A,
    const u16* __restrict__ B, float* __restrict__ C){
  __shared__ u16 As[3][256 * 32];
  __shared__ u16 Bs[3][256 * 32];
  const int gx = gridDim.x, nwg = gx * gridDim.y;
  const int orig = blockIdx.x + blockIdx.y * gx;
  const int wg = (orig & 7) * (nwg >> 3) + (orig >> 3);   // nwg % 8 == 0
  const int m0 = (wg % gx) * 256, n0 = (wg / gx) * 256;
  const int t = threadIdx.x, lane = t & 63;
  const int lr = lane & 15, lk = lane >> 4;
  const int wid = t >> 6, wr = wid >> 2, wc = wid & 3;    // wave tile 128x64
  // staging: load i covers LDS 16B-chunk idx = t + i*512 (row r=idx>>2, phys slot
  // p=idx&3); fetch logical slot p^(r&3) so reads with slot lk^(r&3) see slot lk.
  const u16* gA[2]; const u16* gB[2]; int ldst[2];
#pragma unroll
  for (int i = 0; i < 2; ++i){
    int idx = t + i * 512, r = idx >> 2, pp = idx & 3, sl = pp ^ (r & 3);
    gA[i] = A + (long)(m0 + r) * NE + sl * 8;
    gB[i] = B + (long)(n0 + r) * NE + sl * 8;
    ldst[i] = idx * 8;                   // u16 offset
  }
  auto stage = [&](int buf, int kt){     // 4 gload16 per thread per K-tile
#pragma unroll
    for (int i = 0; i < 2; ++i) gload16(gA[i] + kt * 32, &As[buf][ldst[i]]);
#pragma unroll
    for (int i = 0; i < 2; ++i) gload16(gB[i] + kt * 32, &Bs[buf][ldst[i]]);
  };
  f32x4 acc[8][4] = {};
  const int nk = NE / 32;                // 24 K-tiles
  stage(0, 0);
  stage(1, 1);
  int cur = 0;
  for (int kt = 0; kt < nk; ++kt){
    if (kt + 2 < nk){
      int nxt = cur + 2; if (nxt >= 3) nxt -= 3;   // tile kt+2 -> buf (kt+2)%3
      stage(nxt, kt + 2);
    }
    int rem = nk - 1 - kt;
    waitvm(rem >= 2 ? 8 : rem == 1 ? 4 : 0);       // wait only tile kt's 4 loads
    __builtin_amdgcn_sched_barrier(0);
    __builtin_amdgcn_s_barrier();        // tile kt resident in As/Bs[cur]
    __builtin_amdgcn_sched_barrier(0);
    short8 bf[4];
#pragma unroll
    for (int nj = 0; nj < 4; ++nj){
      int r = wc * 64 + nj * 16 + lr;
      bf[nj] = *(const short8*)&Bs[cur][r * 32 + ((lk ^ (r & 3)) * 8)];
    }
    {
      short8 af[4];
#pragma unroll
      for (int mi = 0; mi < 4; ++mi){
        int r = wr * 128 + mi * 16 + lr;
        af[mi] = *(const short8*)&As[cur][r * 32 + ((lk ^ (r & 3)) * 8)];
      }
      __builtin_amdgcn_s_setprio(1);
#pragma unroll
      for (int mi = 0; mi < 4; ++mi)
#pragma unroll
        for (int nj = 0; nj < 4; ++nj)
          acc[mi][nj] = __builtin_amdgcn_mfma_f32_16x16x32_bf16(af[mi], bf[nj], acc[mi][nj], 0, 0, 0);
      __builtin_amdgcn_s_setprio(0);
    }
    {
      short8 af[4];
#pragma unroll
      for (int mi = 0; mi < 4; ++mi){
        int r = wr * 128 + (mi + 4) * 16 + lr;
        af[mi] = *(const short8*)&As[cur][r * 32 + ((lk ^ (r & 3)) * 8)];
      }
      __builtin_amdgcn_s_setprio(1);
#pragma unroll
      for (int mi = 0; mi < 4; ++mi)
#pragma unroll
        for (int nj = 0; nj < 4; ++nj)
          acc[mi + 4][nj] = __builtin_amdgcn_mfma_f32_16x16x32_bf16(af[mi], bf[nj], acc[mi + 4][nj], 0, 0, 0);
      __builtin_amdgcn_s_setprio(0);
    }
    asm volatile("s_waitcnt lgkmcnt(0)" ::: "memory");  // this wave's ds_reads of cur done
    __builtin_amdgcn_sched_barrier(0);
    __builtin_amdgcn_s_barrier();        // all waves done with cur -> restage next iter
    cur = (cur == 2) ? 0 : cur + 1;
  }
#pragma unroll
  for (int mi = 0; mi < 8; ++mi)
#pragma unroll
    for (int r = 0; r < 4; ++r){
      int row = m0 + wr * 128 + mi * 16 + lk * 4 + r;
#pragma unroll
      for (int nj = 0; nj < 4; ++nj){
        int col = n0 + wc * 64 + nj * 16 + lr;
        if (col < NV) C[(long)row * NV + col] = acc[mi][nj][r];
      }
    }
}

extern "C" void kernel_launch(void* const* d_in, const int* in_sizes, int n_in,
                              void* d_out, int out_size, void* d_ws, size_t ws_size,
                              hipStream_t stream){
  (void)in_sizes; (void)n_in; (void)out_size; (void)ws_size;
  const float* x    = (const float*)d_in[0];
  const float* Wqkv = (const float*)d_in[1];
  const float* bqkv = (const float*)d_in[2];
  const float* Wo   = (const float*)d_in[3];
  const float* bo   = (const float*)d_in[4];
  const float* W1   = (const float*)d_in[5];
  const float* b1   = (const float*)d_in[6];
  const float* W2   = (const float*)d_in[7];
  const float* b2   = (const float*)d_in[8];
  const float* ln1g = (const float*)d_in[9];
  const float* ln1b = (const float*)d_in[10];
  const float* ln2g = (const float*)d_in[11];
  const float* ln2b = (const float*)d_in[12];
  const float* lnfg = (const float*)d_in[13];
  const float* lnfb = (const float*)d_in[14];
  const float* Wlm  = (const float*)d_in[15];

  char* ws = (char*)d_ws;
  size_t off = 0;
  auto alloc = [&](size_t bytes){ void* p = ws + off; off += (bytes + 255) & ~255UL; return p; };
  float* h      = (float*)alloc((size_t)TT * NE * 4);
  u16*   a      = (u16*)  alloc((size_t)TT * NE * 2);
  u16*   qkv    = (u16*)  alloc((size_t)TT * QKVD * 2);
  u16*   vtbuf  = (u16*)  alloc((size_t)NB * NH * HD * SL * 2);
  u16*   attno  = (u16*)  alloc((size_t)TT * NE * 2);
  u16*   ffm    = (u16*)  alloc((size_t)TT * DFF * 2);
  float* part   = (float*)alloc((size_t)4 * TT * NE * 4);
  u16*   wqkvT  = (u16*)  alloc((size_t)NL * QKVD * NE * 2);
  u16*   woT    = (u16*)  alloc((size_t)NL * NE * NE * 2);
  u16*   w1T    = (u16*)  alloc((size_t)NL * DFF * NE * 2);
  u16*   w2T    = (u16*)  alloc((size_t)NL * NE * DFF * 2);
  u16*   wlmB   = (u16*)  alloc((size_t)NVP * NE * 2);

  // h = x
  hipMemcpyAsync(h, x, (size_t)TT * NE * 4, hipMemcpyDeviceToDevice, stream);
  // weight conversions
  k_transpose_cvt_all<<<dim3(QKVD / 32, NE / 32, NL), 256, 0, stream>>>(Wqkv, wqkvT, NE, QKVD);
  k_transpose_cvt_all<<<dim3(NE / 32, NE / 32, NL),   256, 0, stream>>>(Wo,   woT,   NE, NE);
  k_transpose_cvt_all<<<dim3(DFF / 32, NE / 32, NL),  256, 0, stream>>>(W1,   w1T,   NE, DFF);
  k_transpose_cvt_all<<<dim3(NE / 32, DFF / 32, NL),  256, 0, stream>>>(W2,   w2T,   DFF, NE);
  k_cvt4<<<2048, 256, 0, stream>>>((const float4*)Wlm, (u16x4*)wlmB, (long)NV * NE / 4);
  hipMemsetAsync(wlmB + (size_t)NV * NE, 0, (size_t)(NVP - NV) * NE * 2, stream);

  // ln1 of layer 0
  k_layernorm<<<TT, 256, 0, stream>>>(h, ln1g, ln1b, a);

  for (int L = 0; L < NL; ++L){
    // qkv = a @ Wqkv + bqkv ; V columns scattered transposed into vtbuf
    gemm(stream, a, NE, wqkvT + (size_t)L * QKVD * NE, NE, qkv, QKVD, TT, QKVD, NE,
         bqkv + (size_t)L * QKVD, vtbuf, 5);
    // fused causal attention -> attno
    k_flash<<<dim3(NB * NH, SL / 32), 128, 0, stream>>>(qkv, vtbuf, attno);
    // proj: split-K x2 partials
    gemm(stream, attno, NE, woT + (size_t)L * NE * NE, NE, part, NE, TT, NE, 384,
         nullptr, nullptr, 3, 2, 384, 384, (long)TT * NE);
    // h += bo + parts; a = ln2(h)
    k_combine_ln<<<TT, 256, 0, stream>>>(h, part, bo + (size_t)L * NE, 2,
         ln2g + (size_t)L * NE, ln2b + (size_t)L * NE, a);
    // ffm = gelu(a @ W1 + b1)
    gemm(stream, a, NE, w1T + (size_t)L * DFF * NE, NE, ffm, DFF, TT, DFF, NE,
         b1 + (size_t)L * DFF, nullptr, 2);
    // ff2: split-K x4 partials
    gemm(stream, ffm, DFF, w2T + (size_t)L * NE * DFF, DFF, part, NE, TT, NE, 768,
         nullptr, nullptr, 3, 4, 768, 768, (long)TT * NE);
    // h += b2 + parts; a = ln1(next) or lnf (last layer)
    const float* gn = (L + 1 < NL) ? ln1g + (size_t)(L + 1) * NE : lnfg;
    const float* bn = (L + 1 < NL) ? ln1b + (size_t)(L + 1) * NE : lnfb;
    k_combine_ln<<<TT, 256, 0, stream>>>(h, part, b2 + (size_t)L * NE, 4, gn, bn, a);
  }
  // logits = a @ Wlm^T  (f32 out) — 256^2 8-wave BK=32 ring GEMM
  k_gemm256<<<dim3(TT / 256, NVP / 256), 512, 0, stream>>>(a, wlmB, (float*)d_out);
}

// Round 11
// 2437.266 us; speedup vs baseline: 2.0480x; 1.0150x over previous
//
#include <hip/hip_runtime.h>
#include <math.h>

typedef unsigned short u16;
typedef u16 u16x8 __attribute__((ext_vector_type(8)));
typedef u16 u16x4 __attribute__((ext_vector_type(4)));
typedef short short8 __attribute__((ext_vector_type(8)));
typedef float f32x4 __attribute__((ext_vector_type(4)));

#define NE 768
#define NH 12
#define NL 12
#define NV 50257
#define NVP 50432   // NV padded to 256 multiple for the 256^2 LM-head GEMM
#define HD 64
#define DFF 3072
#define NB 2
#define SL 1024
#define TT 2048     // NB*SL tokens
#define QKVD 2304   // 3*NE

static __device__ __forceinline__ u16 f2bf(float f){
  unsigned int x; __builtin_memcpy(&x, &f, 4);
  x = (x + 0x7FFFu + ((x >> 16) & 1u)) >> 16;
  return (u16)x;
}

typedef const __attribute__((address_space(1))) unsigned int* gas1_t;
typedef __attribute__((address_space(3))) unsigned int* las3_t;
static __device__ __forceinline__ void gload16(const u16* g, u16* l){
  __builtin_amdgcn_global_load_lds((gas1_t)(const void*)g, (las3_t)(void*)l, 16, 0, 0);
}
// counted vmcnt wait: N loads may remain in flight (wave-uniform arg)
static __device__ __forceinline__ void waitvm(int n){
  switch (n){
    case 0: asm volatile("s_waitcnt vmcnt(0)" ::: "memory"); break;
    case 3: asm volatile("s_waitcnt vmcnt(3)" ::: "memory"); break;
    case 4: asm volatile("s_waitcnt vmcnt(4)" ::: "memory"); break;
    case 6: asm volatile("s_waitcnt vmcnt(6)" ::: "memory"); break;
    default: asm volatile("s_waitcnt vmcnt(8)" ::: "memory"); break;
  }
}

// ---------------- fp32 -> bf16 convert (vectorized) ----------------
__global__ void k_cvt4(const float4* __restrict__ in, u16x4* __restrict__ out, long n4){
  long i = (long)blockIdx.x * blockDim.x + threadIdx.x;
  long st = (long)gridDim.x * blockDim.x;
  for (; i < n4; i += st){
    float4 v = in[i];
    u16x4 o = { f2bf(v.x), f2bf(v.y), f2bf(v.z), f2bf(v.w) };
    out[i] = o;
  }
}

// ------ fp32 [L][K][N] -> bf16 [L][N][K] transpose-convert, all layers ------
// Vectorized: float4 reads, u16x4 writes. Tile: 32 K-rows x 128 N-cols.
// grid (N/128, K/32, NL), 256 threads.
__global__ __launch_bounds__(256) void k_transpose_cvt_all(const float* __restrict__ in0,
    u16* __restrict__ out0, int K, int N){
  __shared__ u16 tile[128][33];          // [n within 128][k within 32], +1 pad
  const float* in = in0 + (long)blockIdx.z * K * N;
  u16* out = out0 + (long)blockIdx.z * N * K;
  const int n0 = blockIdx.x * 128, k0 = blockIdx.y * 32;
  const int t = threadIdx.x;
#pragma unroll
  for (int i = 0; i < 4; ++i){
    int e = t + i * 256;                 // [0,1024)
    int r = e >> 5, c = e & 31;          // r: k-row [0,32), c: float4 col [0,32)
    float4 v = *(const float4*)(in + (long)(k0 + r) * N + n0 + c * 4);
    tile[c * 4 + 0][r] = f2bf(v.x);
    tile[c * 4 + 1][r] = f2bf(v.y);
    tile[c * 4 + 2][r] = f2bf(v.z);
    tile[c * 4 + 3][r] = f2bf(v.w);
  }
  __syncthreads();
#pragma unroll
  for (int i = 0; i < 4; ++i){
    int e = t + i * 256;                 // [0,1024)
    int nr = e >> 3, kc = e & 7;         // nr: n-row [0,128), kc: u16x4 chunk [0,8)
    u16x4 o = { tile[nr][kc * 4 + 0], tile[nr][kc * 4 + 1],
                tile[nr][kc * 4 + 2], tile[nr][kc * 4 + 3] };
    *(u16x4*)(out + (long)(n0 + nr) * K + k0 + kc * 4) = o;
  }
}

// ---------------- LayerNorm: f32 [TT][768] -> bf16 ----------------
__global__ __launch_bounds__(256) void k_layernorm(const float* __restrict__ x,
    const float* __restrict__ g, const float* __restrict__ b, u16* __restrict__ out){
  int row = blockIdx.x;
  const float* xr = x + (long)row * NE;
  int t = threadIdx.x;
  float v[3];
  v[0] = xr[t]; v[1] = xr[t + 256]; v[2] = xr[t + 512];
  float s = v[0] + v[1] + v[2];
  float sq = v[0]*v[0] + v[1]*v[1] + v[2]*v[2];
  __shared__ float red[8];
#pragma unroll
  for (int o = 32; o; o >>= 1){ s += __shfl_xor(s, o); sq += __shfl_xor(sq, o); }
  int wid = t >> 6, lane = t & 63;
  if (!lane){ red[wid] = s; red[4 + wid] = sq; }
  __syncthreads();
  s  = red[0] + red[1] + red[2] + red[3];
  sq = red[4] + red[5] + red[6] + red[7];
  float mean = s * (1.f / NE);
  float var  = sq * (1.f / NE) - mean * mean;
  float rs = rsqrtf(var + 1e-5f);
  u16* orow = out + (long)row * NE;
#pragma unroll
  for (int i = 0; i < 3; ++i){
    int c = t + i * 256;
    orow[c] = f2bf((v[i] - mean) * rs * g[c] + b[c]);
  }
}

// ---- split-K combine + LayerNorm fused: one block per token row ----
__global__ __launch_bounds__(256) void k_combine_ln(float* __restrict__ h,
    const float* __restrict__ part, const float* __restrict__ bias, int nsplit,
    const float* __restrict__ g, const float* __restrict__ b, u16* __restrict__ aout){
  int row = blockIdx.x;
  int t = threadIdx.x;
  float* hr = h + (long)row * NE;
  float v[3];
#pragma unroll
  for (int i = 0; i < 3; ++i){
    int c = t + i * 256;
    float acc = hr[c] + bias[c];
    for (int s = 0; s < nsplit; ++s)
      acc += part[(long)s * TT * NE + (long)row * NE + c];
    v[i] = acc;
    hr[c] = acc;
  }
  float s = v[0] + v[1] + v[2];
  float sq = v[0]*v[0] + v[1]*v[1] + v[2]*v[2];
  __shared__ float red[8];
#pragma unroll
  for (int o = 32; o; o >>= 1){ s += __shfl_xor(s, o); sq += __shfl_xor(sq, o); }
  int wid = t >> 6, lane = t & 63;
  if (!lane){ red[wid] = s; red[4 + wid] = sq; }
  __syncthreads();
  s  = red[0] + red[1] + red[2] + red[3];
  sq = red[4] + red[5] + red[6] + red[7];
  float mean = s * (1.f / NE);
  float var  = sq * (1.f / NE) - mean * mean;
  float rs = rsqrtf(var + 1e-5f);
  u16* orow = aout + (long)row * NE;
#pragma unroll
  for (int i = 0; i < 3; ++i){
    int c = t + i * 256;
    orow[c] = f2bf((v[i] - mean) * rs * g[c] + b[c]);
  }
}

// ---------------- barrier-free fused causal flash attention ----------------
// 2-wave blocks, 32 q-rows per block, grid (24 bh, 32 q-tiles) heavy-first.
__global__ __launch_bounds__(128) void k_flash(const u16* __restrict__ qkv,
    const u16* __restrict__ vt, u16* __restrict__ out){
  __shared__ u16 Ps[2][16][72];          // wave-private P tile (q x kv)
  const int z = blockIdx.x;
  const int qt = gridDim.y - 1 - blockIdx.y;   // heavy q-tiles dispatch first
  const int b = z / NH, h = z % NH;
  const int t = threadIdx.x, lane = t & 63, wid = t >> 6;
  const int lr = lane & 15, lk = lane >> 4;
  const int qr0 = qt * 32 + wid * 16;    // wave's first q row
  const u16* Qp = qkv + (long)(b * SL + qr0 + lr) * QKVD + h * HD;
  short8 aq[2];
  aq[0] = *(const short8*)(Qp + lk * 8);
  aq[1] = *(const short8*)(Qp + 32 + lk * 8);
  const u16* Kb  = qkv + (long)(b * SL) * QKVD + NE + h * HD;
  const u16* Vtb = vt + (long)z * HD * SL;
  f32x4 o[4] = {};
  float m[4], l[4];
#pragma unroll
  for (int r = 0; r < 4; ++r){ m[r] = -3e38f; l[r] = 0.f; }
  const int nt = (qt * 32 + 31) / 64 + 1;
  for (int kt = 0; kt < nt; ++kt){
    const int kv0 = kt * 64;
    short8 kb[4][2];
#pragma unroll
    for (int j = 0; j < 4; ++j)
#pragma unroll
      for (int c = 0; c < 2; ++c)
        kb[j][c] = *(const short8*)(Kb + (long)(kv0 + j * 16 + lr) * QKVD + c * 32 + lk * 8);
    f32x4 s[4] = {};
#pragma unroll
    for (int c = 0; c < 2; ++c)
#pragma unroll
      for (int j = 0; j < 4; ++j)
        s[j] = __builtin_amdgcn_mfma_f32_16x16x32_bf16(aq[c], kb[j][c], s[j], 0, 0, 0);
    const bool dm = (kt == nt - 1);
#pragma unroll
    for (int r = 0; r < 4; ++r){
      const int row = qr0 + lk * 4 + r;
      float pm = -3e38f;
#pragma unroll
      for (int j = 0; j < 4; ++j){
        float v = s[j][r] * 0.125f;
        if (dm && (kv0 + j * 16 + lr > row)) v = -3e38f;
        s[j][r] = v;
        pm = fmaxf(pm, v);
      }
#pragma unroll
      for (int off = 1; off < 16; off <<= 1) pm = fmaxf(pm, __shfl_xor(pm, off));
      float mn = fmaxf(m[r], pm);
      float f = __expf(m[r] - mn);
      m[r] = mn;
      float ps = 0.f;
#pragma unroll
      for (int j = 0; j < 4; ++j){
        float pv = __expf(s[j][r] - mn);
        ps += pv;
        Ps[wid][lk * 4 + r][j * 16 + lr] = f2bf(pv);
      }
#pragma unroll
      for (int off = 1; off < 16; off <<= 1) ps += __shfl_xor(ps, off);
      l[r] = l[r] * f + ps;
#pragma unroll
      for (int j = 0; j < 4; ++j) o[j][r] *= f;
    }
#pragma unroll
    for (int c = 0; c < 2; ++c){
      short8 pa = *(const short8*)&Ps[wid][lr][c * 32 + lk * 8];
#pragma unroll
      for (int j = 0; j < 4; ++j){
        short8 vb = *(const short8*)(Vtb + (long)(j * 16 + lr) * SL + kv0 + c * 32 + lk * 8);
        o[j] = __builtin_amdgcn_mfma_f32_16x16x32_bf16(pa, vb, o[j], 0, 0, 0);
      }
    }
  }
  u16* O = out + (long)(b * SL) * NE + h * HD;
#pragma unroll
  for (int r = 0; r < 4; ++r){
    float inv = 1.f / l[r];
    const int row = qr0 + lk * 4 + r;
#pragma unroll
    for (int j = 0; j < 4; ++j)
      O[(long)row * NE + j * 16 + lr] = f2bf(o[j][r] * inv);
  }
}

// --- generic bf16 MFMA GEMM, 64x128 tile, B^T layout, 3-buf counted-vmcnt ring ---
// modes: 2 bf16 +bias +gelu(erf), 3 f32 raw, 5 qkv: bf16 +bias, V cols scattered to vt
struct GemmP {
  const u16* A; const u16* B; void* C;
  const float* bias; u16* vt;
  int M, N, K, lda, ldb, ldc, mode;
  long zA, zB, zC;                       // per-blockIdx.z element offsets (split-K)
};

__global__ __launch_bounds__(256) void k_gemm_bt(GemmP p){
  __shared__ u16 As[3][64 * 32];
  __shared__ u16 Bs[3][128 * 32];
  // XCD-aware block swizzle (nwg is always a multiple of 8 here)
  const int nwg = gridDim.x * gridDim.y;
  const int orig = blockIdx.x + blockIdx.y * gridDim.x;
  const int wg = (orig & 7) * (nwg >> 3) + (orig >> 3);
  const int m0 = (wg % gridDim.x) * 64, n0 = (wg / gridDim.x) * 128;
  const u16* A = p.A + (long)blockIdx.z * p.zA;
  const u16* B = p.B + (long)blockIdx.z * p.zB;
  const long offC = (long)blockIdx.z * p.zC;
  const int t = threadIdx.x, lane = t & 63, wid = t >> 6;
  const int wm = (wid >> 1) * 32, wn = (wid & 1) * 64;
  const int lr = lane & 15, lk = lane >> 4;
  const int srow = t >> 2;               // [0,64)
  const int sseg = (t & 3) * 8;
  const u16* Abase  = A + (long)(m0 + srow) * p.lda + sseg;
  const u16* Bbase  = B + (long)(n0 + srow) * p.ldb + sseg;
  const u16* Bbase2 = B + (long)(n0 + 64 + srow) * p.ldb + sseg;
  auto stage = [&](int buf, int kt){     // 3 gload_lds per thread per K-tile
    gload16(Abase  + kt * 32, &As[buf][t * 8]);
    gload16(Bbase  + kt * 32, &Bs[buf][t * 8]);
    gload16(Bbase2 + kt * 32, &Bs[buf][(t + 256) * 8]);
  };
  f32x4 acc[2][4] = {};
  const int nk = p.K >> 5;               // always >= 2 here
  stage(0, 0);
  stage(1, 1);
  int cur = 0;
  for (int kt = 0; kt < nk; ++kt){
    if (kt + 2 < nk){
      int nxt = cur + 2; if (nxt >= 3) nxt -= 3;   // tile kt+2 -> buf (kt+2)%3
      stage(nxt, kt + 2);
    }
    // wait only this tile's 3 loads; leave up to 6 (tiles kt+1, kt+2) in flight
    int rem = nk - 1 - kt;
    waitvm(rem >= 2 ? 6 : rem == 1 ? 3 : 0);
    __builtin_amdgcn_s_barrier();        // all waves' tile-kt loads complete
    short8 af[2], bfr[4];
#pragma unroll
    for (int i = 0; i < 2; ++i) af[i]  = *(const short8*)&As[cur][(wm + i * 16 + lr) * 32 + lk * 8];
#pragma unroll
    for (int j = 0; j < 4; ++j) bfr[j] = *(const short8*)&Bs[cur][(wn + j * 16 + lr) * 32 + lk * 8];
#pragma unroll
    for (int i = 0; i < 2; ++i)
#pragma unroll
      for (int j = 0; j < 4; ++j)
        acc[i][j] = __builtin_amdgcn_mfma_f32_16x16x32_bf16(af[i], bfr[j], acc[i][j], 0, 0, 0);
    asm volatile("s_waitcnt lgkmcnt(0)" ::: "memory");  // ds_reads of buf done
    __builtin_amdgcn_s_barrier();        // before buf is restaged next iter
    cur = (cur == 2) ? 0 : cur + 1;
  }
#pragma unroll
  for (int i = 0; i < 2; ++i){
#pragma unroll
    for (int r = 0; r < 4; ++r){
      int row = m0 + wm + i * 16 + lk * 4 + r;
      if (row >= p.M) continue;
#pragma unroll
      for (int j = 0; j < 4; ++j){
        int col = n0 + wn + j * 16 + lr;
        if (col >= p.N) continue;
        float v = acc[i][j][r];
        long idx = offC + (long)row * p.ldc + col;
        if (p.mode == 5){
          v += p.bias[col];
          if (col >= 2 * NE){
            int d = col - 2 * NE;
            long vidx = (((long)(row >> 10) * NH + (d >> 6)) * HD + (d & 63)) * SL + (row & 1023);
            p.vt[vidx] = f2bf(v);
          } else {
            ((u16*)p.C)[idx] = f2bf(v);
          }
        } else if (p.mode == 2){
          v += p.bias[col];
          v = 0.5f * v * (1.f + erff(v * 0.70710678118f));
          ((u16*)p.C)[idx] = f2bf(v);
        } else {
          ((float*)p.C)[idx] = v;
        }
      }
    }
  }
}

static inline void gemm(hipStream_t s, const u16* A, int lda, const u16* B, int ldb,
    void* C, int ldc, int M, int N, int K, const float* bias, u16* vt, int mode,
    int gz = 1, long zA = 0, long zB = 0, long zC = 0){
  GemmP p{ A, B, C, bias, vt, M, N, K, lda, ldb, ldc, mode, zA, zB, zC };
  dim3 g(M / 64, (N + 127) / 128, gz);
  k_gemm_bt<<<g, 256, 0, s>>>(p);
}

// ======== 256x256 8-wave LM-head GEMM (r8-proven): BK=64, 2-buf depth-1 ========
// T2 XOR-swizzled LDS (linear gload_lds dest + pre-swizzled global src, rule #21),
// T4 counted vmcnt(8) across barriers, T5 setprio around MFMA clusters.
__global__ __launch_bounds__(512, 1) void k_gemm256(const u16* __restrict__ A,
    const u16* __restrict__ B, float* __restrict__ C){
  __shared__ u16 As[2][256 * 64];
  __shared__ u16 Bs[2][256 * 64];
  const int gx = gridDim.x, nwg = gx * gridDim.y;
  const int orig = blockIdx.x + blockIdx.y * gx;
  const int wg = (orig & 7) * (nwg >> 3) + (orig >> 3);   // nwg % 8 == 0
  const int m0 = (wg % gx) * 256, n0 = (wg / gx) * 256;
  const int t = threadIdx.x, lane = t & 63;
  const int lr = lane & 15, lk = lane >> 4;
  const int wid = t >> 6, wr = wid >> 2, wc = wid & 3;    // wave tile 128x64
  // staging: load i covers physical LDS bytes tt*16 (tt = t + i*512):
  // row r = tt>>3, phys slot p = tt&7; fetch logical slot p^(r&7) (swizzle involution)
  const u16* gA[4]; const u16* gB[4]; int ldst[4];
#pragma unroll
  for (int i = 0; i < 4; ++i){
    int tt = t + i * 512, r = tt >> 3, pp = tt & 7, sl = pp ^ (r & 7);
    gA[i] = A + (long)(m0 + r) * NE + sl * 8;
    gB[i] = B + (long)(n0 + r) * NE + sl * 8;
    ldst[i] = tt * 8;                    // u16 offset
  }
  auto stage = [&](int buf, int kt){     // 8 gload16 per thread
#pragma unroll
    for (int i = 0; i < 4; ++i) gload16(gA[i] + kt * 64, &As[buf][ldst[i]]);
#pragma unroll
    for (int i = 0; i < 4; ++i) gload16(gB[i] + kt * 64, &Bs[buf][ldst[i]]);
  };
  // swizzled fragment reads: logical u16 col (kc*32+lk*8) ^ ((row&7)<<3)
  f32x4 acc[8][4] = {};
  const int nk = NE / 64;                // 12 K-tiles
  stage(0, 0);
  for (int kt = 0; kt < nk; ++kt){
    const int buf = kt & 1;
    if (kt + 1 < nk){ stage(buf ^ 1, kt + 1); waitvm(8); }
    else            { waitvm(0); }
    __builtin_amdgcn_sched_barrier(0);
    __builtin_amdgcn_s_barrier();        // tile kt resident in As/Bs[buf]
    __builtin_amdgcn_sched_barrier(0);
    short8 bf[4][2];
#pragma unroll
    for (int nj = 0; nj < 4; ++nj)
#pragma unroll
      for (int kc = 0; kc < 2; ++kc){
        int r = wc * 64 + nj * 16 + lr;
        bf[nj][kc] = *(const short8*)&Bs[buf][r * 64 + ((kc * 32 + lk * 8) ^ ((r & 7) << 3))];
      }
    {
      short8 af[4][2];
#pragma unroll
      for (int mi = 0; mi < 4; ++mi)
#pragma unroll
        for (int kc = 0; kc < 2; ++kc){
          int r = wr * 128 + mi * 16 + lr;
          af[mi][kc] = *(const short8*)&As[buf][r * 64 + ((kc * 32 + lk * 8) ^ ((r & 7) << 3))];
        }
      __builtin_amdgcn_s_setprio(1);
#pragma unroll
      for (int mi = 0; mi < 4; ++mi)
#pragma unroll
        for (int nj = 0; nj < 4; ++nj)
#pragma unroll
          for (int kc = 0; kc < 2; ++kc)
            acc[mi][nj] = __builtin_amdgcn_mfma_f32_16x16x32_bf16(af[mi][kc], bf[nj][kc], acc[mi][nj], 0, 0, 0);
      __builtin_amdgcn_s_setprio(0);
    }
    {
      short8 af[4][2];
#pragma unroll
      for (int mi = 0; mi < 4; ++mi)
#pragma unroll
        for (int kc = 0; kc < 2; ++kc){
          int r = wr * 128 + (mi + 4) * 16 + lr;
          af[mi][kc] = *(const short8*)&As[buf][r * 64 + ((kc * 32 + lk * 8) ^ ((r & 7) << 3))];
        }
      __builtin_amdgcn_s_setprio(1);
#pragma unroll
      for (int mi = 0; mi < 4; ++mi)
#pragma unroll
        for (int nj = 0; nj < 4; ++nj)
#pragma unroll
          for (int kc = 0; kc < 2; ++kc)
            acc[mi + 4][nj] = __builtin_amdgcn_mfma_f32_16x16x32_bf16(af[mi][kc], bf[nj][kc], acc[mi + 4][nj], 0, 0, 0);
      __builtin_amdgcn_s_setprio(0);
    }
    asm volatile("s_waitcnt lgkmcnt(0)" ::: "memory");  // this wave's ds_reads of buf done
    __builtin_amdgcn_sched_barrier(0);
    __builtin_amdgcn_s_barrier();        // all waves done with buf -> restage next iter
  }
#pragma unroll
  for (int mi = 0; mi < 8; ++mi)
#pragma unroll
    for (int r = 0; r < 4; ++r){
      int row = m0 + wr * 128 + mi * 16 + lk * 4 + r;
#pragma unroll
      for (int nj = 0; nj < 4; ++nj){
        int col = n0 + wc * 64 + nj * 16 + lr;
        if (col < NV) C[(long)row * NV + col] = acc[mi][nj][r];
      }
    }
}

extern "C" void kernel_launch(void* const* d_in, const int* in_sizes, int n_in,
                              void* d_out, int out_size, void* d_ws, size_t ws_size,
                              hipStream_t stream){
  (void)in_sizes; (void)n_in; (void)out_size; (void)ws_size;
  const float* x    = (const float*)d_in[0];
  const float* Wqkv = (const float*)d_in[1];
  const float* bqkv = (const float*)d_in[2];
  const float* Wo   = (const float*)d_in[3];
  const float* bo   = (const float*)d_in[4];
  const float* W1   = (const float*)d_in[5];
  const float* b1   = (const float*)d_in[6];
  const float* W2   = (const float*)d_in[7];
  const float* b2   = (const float*)d_in[8];
  const float* ln1g = (const float*)d_in[9];
  const float* ln1b = (const float*)d_in[10];
  const float* ln2g = (const float*)d_in[11];
  const float* ln2b = (const float*)d_in[12];
  const float* lnfg = (const float*)d_in[13];
  const float* lnfb = (const float*)d_in[14];
  const float* Wlm  = (const float*)d_in[15];

  char* ws = (char*)d_ws;
  size_t off = 0;
  auto alloc = [&](size_t bytes){ void* p = ws + off; off += (bytes + 255) & ~255UL; return p; };
  float* h      = (float*)alloc((size_t)TT * NE * 4);
  u16*   a      = (u16*)  alloc((size_t)TT * NE * 2);
  u16*   qkv    = (u16*)  alloc((size_t)TT * QKVD * 2);
  u16*   vtbuf  = (u16*)  alloc((size_t)NB * NH * HD * SL * 2);
  u16*   attno  = (u16*)  alloc((size_t)TT * NE * 2);
  u16*   ffm    = (u16*)  alloc((size_t)TT * DFF * 2);
  float* part   = (float*)alloc((size_t)4 * TT * NE * 4);
  u16*   wqkvT  = (u16*)  alloc((size_t)NL * QKVD * NE * 2);
  u16*   woT    = (u16*)  alloc((size_t)NL * NE * NE * 2);
  u16*   w1T    = (u16*)  alloc((size_t)NL * DFF * NE * 2);
  u16*   w2T    = (u16*)  alloc((size_t)NL * NE * DFF * 2);
  u16*   wlmB   = (u16*)  alloc((size_t)NVP * NE * 2);

  // h = x
  hipMemcpyAsync(h, x, (size_t)TT * NE * 4, hipMemcpyDeviceToDevice, stream);
  // weight conversions (vectorized transpose: grid N/128 x K/32 x NL)
  k_transpose_cvt_all<<<dim3(QKVD / 128, NE / 32, NL), 256, 0, stream>>>(Wqkv, wqkvT, NE, QKVD);
  k_transpose_cvt_all<<<dim3(NE / 128, NE / 32, NL),   256, 0, stream>>>(Wo,   woT,   NE, NE);
  k_transpose_cvt_all<<<dim3(DFF / 128, NE / 32, NL),  256, 0, stream>>>(W1,   w1T,   NE, DFF);
  k_transpose_cvt_all<<<dim3(NE / 128, DFF / 32, NL),  256, 0, stream>>>(W2,   w2T,   DFF, NE);
  k_cvt4<<<2048, 256, 0, stream>>>((const float4*)Wlm, (u16x4*)wlmB, (long)NV * NE / 4);
  hipMemsetAsync(wlmB + (size_t)NV * NE, 0, (size_t)(NVP - NV) * NE * 2, stream);

  // ln1 of layer 0
  k_layernorm<<<TT, 256, 0, stream>>>(h, ln1g, ln1b, a);

  for (int L = 0; L < NL; ++L){
    // qkv = a @ Wqkv + bqkv ; V columns scattered transposed into vtbuf
    gemm(stream, a, NE, wqkvT + (size_t)L * QKVD * NE, NE, qkv, QKVD, TT, QKVD, NE,
         bqkv + (size_t)L * QKVD, vtbuf, 5);
    // fused causal attention -> attno
    k_flash<<<dim3(NB * NH, SL / 32), 128, 0, stream>>>(qkv, vtbuf, attno);
    // proj: split-K x2 partials
    gemm(stream, attno, NE, woT + (size_t)L * NE * NE, NE, part, NE, TT, NE, 384,
         nullptr, nullptr, 3, 2, 384, 384, (long)TT * NE);
    // h += bo + parts; a = ln2(h)
    k_combine_ln<<<TT, 256, 0, stream>>>(h, part, bo + (size_t)L * NE, 2,
         ln2g + (size_t)L * NE, ln2b + (size_t)L * NE, a);
    // ffm = gelu(a @ W1 + b1)
    gemm(stream, a, NE, w1T + (size_t)L * DFF * NE, NE, ffm, DFF, TT, DFF, NE,
         b1 + (size_t)L * DFF, nullptr, 2);
    // ff2: split-K x4 partials
    gemm(stream, ffm, DFF, w2T + (size_t)L * NE * DFF, DFF, part, NE, TT, NE, 768,
         nullptr, nullptr, 3, 4, 768, 768, (long)TT * NE);
    // h += b2 + parts; a = ln1(next) or lnf (last layer)
    const float* gn = (L + 1 < NL) ? ln1g + (size_t)(L + 1) * NE : lnfg;
    const float* bn = (L + 1 < NL) ? ln1b + (size_t)(L + 1) * NE : lnfb;
    k_combine_ln<<<TT, 256, 0, stream>>>(h, part, b2 + (size_t)L * NE, 4, gn, bn, a);
  }
  // logits = a @ Wlm^T  (f32 out) — 256^2 8-wave pipelined GEMM
  k_gemm256<<<dim3(TT / 256, NVP / 256), 512, 0, stream>>>(a, wlmB, (float*)d_out);
}